// Round 7
// baseline (206.780 us; speedup 1.0000x reference)
//
#include <hip/hip_runtime.h>
#include <hip/hip_bf16.h>

// AttentionConv2d: B=8, C_IN=256, H=W=32 (HW=1024), DK=DV=256, NH=8, DKH=DVH=32,
// C_OUT=512, 3x3 conv pad=1. fp32 storage in/out; bf16 intermediates + MFMA.
//
// Workspace (bf16 elements, EXACTLY 16 MB = 8,388,608 bf16 — proven safe size):
//   xT    [8 b][1024 l][256 ci]  @ 0          (dead after qkv)  } aliased later by
//   attL  [8 b][1024 l][256 ch]  @ 0          (attn -> attnout) } each other
//   wo_bf chunk-blocked          @ 2,097,152  (589,824; dead after conv3)
//   qT    [64 head][1024][32]    @ 2,097,152  (written by qkv AFTER conv3 -> safe alias)
//   kR    [64 head][1024][32]    @ 4,194,304
//   vW    [64 head][32][1024]    @ 6,291,456  (ends exactly 8,388,608)
// Kernel order: prep -> conv3 -> qkv -> attn -> attnout (stream-serial).

typedef __hip_bfloat16 bf16;
typedef __attribute__((ext_vector_type(8))) short bf16x8;
typedef __attribute__((ext_vector_type(4))) float f32x4;

__device__ __forceinline__ float bf2f(bf16 v) { return __bfloat162float(v); }
__device__ __forceinline__ float blo(unsigned int v) { return __uint_as_float(v << 16); }
__device__ __forceinline__ float bhi(unsigned int v) { return __uint_as_float(v & 0xffff0000u); }
__device__ __forceinline__ unsigned short f2bfbits(float f) {
  union { bf16 h; unsigned short u; } cv; cv.h = __float2bfloat16(f); return cv.u;
}
// cheap round-to-nearest (ties away): 2 VALU ops vs ~4 for RNE; <=1 ulp diff.
__device__ __forceinline__ short f2bfr(float f) {
  return (short)((__float_as_uint(f) + 0x8000u) >> 16);
}

// ---------------------------------------------------------------------------
// K0: prep — xT transpose to bf16 + w_out bf16 chunk-blocked.
// blocks 0..2047: xT; 2048..2083: w_out. grid 2084.
// w_out_bf layout: [(co>>6)*8 + (ci>>5)][co&63][kidx 9][ci&31]  (18432 bf16/chunkblk)
// ---------------------------------------------------------------------------
__global__ __launch_bounds__(256) void prep_kernel(
    const float* __restrict__ x, const float* __restrict__ wout,
    bf16* __restrict__ xT, bf16* __restrict__ wo_bf)
{
  int bid = blockIdx.x, tid = threadIdx.x;
  if (bid < 2048) {
    __shared__ float t[32 * 33];
    int b = bid >> 8, rem = bid & 255;
    int ci0 = (rem >> 5) * 32, l0 = (rem & 31) * 32;
    {
      int ciL = tid >> 3, lL4 = (tid & 7) * 4;
      float4 v = *(const float4*)(x + (size_t)(b * 256 + ci0 + ciL) * 1024 + l0 + lL4);
      t[ciL * 33 + lL4 + 0] = v.x; t[ciL * 33 + lL4 + 1] = v.y;
      t[ciL * 33 + lL4 + 2] = v.z; t[ciL * 33 + lL4 + 3] = v.w;
    }
    __syncthreads();
    {
      int lL = tid >> 3, cS = (tid & 7) * 4;
      unsigned int p0 = (unsigned int)f2bfbits(t[(cS + 0) * 33 + lL]) |
                        ((unsigned int)f2bfbits(t[(cS + 1) * 33 + lL]) << 16);
      unsigned int p1 = (unsigned int)f2bfbits(t[(cS + 2) * 33 + lL]) |
                        ((unsigned int)f2bfbits(t[(cS + 3) * 33 + lL]) << 16);
      uint2 u2; u2.x = p0; u2.y = p1;
      *(uint2*)(xT + ((size_t)(b * 1024) + l0 + lL) * 256 + ci0 + cS) = u2;
    }
  } else {
    int t0 = (bid - 2048) * 256 + tid;       // 0..9215
#pragma unroll
    for (int s = 0; s < 8; ++s) {
      int u = s * 9216 + t0;                 // dst uint4 index 0..73727
      int chunkblk = u / 2304;
      int within = u - chunkblk * 2304;
      int co63 = within / 36;
      int r = within - co63 * 36;            // kidx*4 + cig
      int kidx = r >> 2, cig = r & 3;
      int co = (chunkblk >> 3) * 64 + co63;
      int ci = (chunkblk & 7) * 32 + cig * 8;
      union { unsigned short h[8]; uint4 u4; } pk;
#pragma unroll
      for (int j = 0; j < 8; ++j)
        pk.h[j] = f2bfbits(wout[(size_t)(co * 256 + ci + j) * 9 + kidx]);
      *(uint4*)(wo_bf + (size_t)u * 8) = pk.u4;
    }
  }
}

// ---------------------------------------------------------------------------
// K1: 3x3 conv 256->256 via 9 shift-GEMMs, MFMA bf16.
// Block: 64 co x 128 spatial (4 rows). grid 256 = b(8) x cotile(4) x rowchunk(8).
// LDS: wS[64 co][296] (288 = 9 kidx * 32 ci), xS[6 rows][34 cols][40] (32 ci used).
// R7: register prefetch of next chunk's w (9x uint4) + x (3x uint4); halo
// zeroing hoisted out of the K-loop (cells never overwritten).
// ---------------------------------------------------------------------------
__global__ __launch_bounds__(256) void conv3_mfma_kernel(
    const bf16* __restrict__ xT, const bf16* __restrict__ wo_bf,
    const float* __restrict__ bias, float* __restrict__ out)
{
  __shared__ __align__(16) short smem[27104];
  short* wS = smem;            // 64*296 = 18944
  short* xS = smem + 18944;    // 6*34*40 = 8160

  int tid = threadIdx.x, lane = tid & 63, wave = tid >> 6;
  int m16 = lane & 15, quad = lane >> 4;
  int bid = blockIdx.x;
  int rc = bid & 7, cotile = (bid >> 3) & 3, b = bid >> 5;
  int y0 = rc * 4;

  // per-thread staging geometry (chunk-invariant)
  int wdst[9];
#pragma unroll
  for (int r = 0; r < 9; ++r) {
    int u = r * 256 + tid;
    wdst[r] = (u / 36) * 296 + (u % 36) * 8;
  }
  int xrow[3], xcol[3], xseg[3];
  bool xok[3];
#pragma unroll
  for (int r = 0; r < 3; ++r) {
    int u = r * 256 + tid;
    int pos = u >> 2; xseg[r] = u & 3;
    xrow[r] = pos >> 5; xcol[r] = pos & 31;
    int gy = y0 - 1 + xrow[r];
    xok[r] = (gy >= 0 && gy < 32);
  }

  // halo zero once (x=-1 and x=32 columns; never overwritten in K-loop)
  if (tid < 48) {
    int pos = tid >> 2, seg = tid & 3;
    int row = pos >> 1, side = pos & 1;
    *(uint4*)(xS + (row * 34 + side * 33) * 40 + seg * 8) = make_uint4(0u, 0u, 0u, 0u);
  }

  const bf16* wbase0 = wo_bf + (size_t)(cotile * 8) * 18432;
  uint4 wreg[9], xreg[3];
#pragma unroll
  for (int r = 0; r < 9; ++r)
    wreg[r] = *(const uint4*)(wbase0 + (size_t)(r * 256 + tid) * 8);
#pragma unroll
  for (int r = 0; r < 3; ++r) {
    uint4 val = make_uint4(0u, 0u, 0u, 0u);
    if (xok[r])
      val = *(const uint4*)(xT + ((size_t)(b * 1024) + (y0 - 1 + xrow[r]) * 32 + xcol[r]) * 256
                             + xseg[r] * 8);
    xreg[r] = val;
  }

  f32x4 acc[8];
#pragma unroll
  for (int t = 0; t < 8; ++t) acc[t] = (f32x4){0.f, 0.f, 0.f, 0.f};

  for (int ck = 0; ck < 8; ++ck) {
    __syncthreads();                          // previous compute done with LDS
#pragma unroll
    for (int r = 0; r < 9; ++r) *(uint4*)(wS + wdst[r]) = wreg[r];
#pragma unroll
    for (int r = 0; r < 3; ++r)
      *(uint4*)(xS + (xrow[r] * 34 + xcol[r] + 1) * 40 + xseg[r] * 8) = xreg[r];
    if (ck < 7) {                             // prefetch next chunk (overlaps MFMA)
      const bf16* wb = wbase0 + (size_t)(ck + 1) * 18432;
#pragma unroll
      for (int r = 0; r < 9; ++r)
        wreg[r] = *(const uint4*)(wb + (size_t)(r * 256 + tid) * 8);
#pragma unroll
      for (int r = 0; r < 3; ++r) {
        uint4 val = make_uint4(0u, 0u, 0u, 0u);
        if (xok[r])
          val = *(const uint4*)(xT + ((size_t)(b * 1024) + (y0 - 1 + xrow[r]) * 32 + xcol[r]) * 256
                                 + (ck + 1) * 32 + xseg[r] * 8);
        xreg[r] = val;
      }
    }
    __syncthreads();                          // staging visible
#pragma unroll
    for (int kidx = 0; kidx < 9; ++kidx) {
      int dy = kidx / 3, dx = kidx - dy * 3;
      bf16x8 af = *(const bf16x8*)(wS + (wave * 16 + m16) * 296 + kidx * 32 + quad * 8);
#pragma unroll
      for (int t = 0; t < 8; ++t) {
        int row = (t >> 1) + dy;
        int col = (t & 1) * 16 + m16 + dx;
        bf16x8 bf = *(const bf16x8*)(xS + (row * 34 + col) * 40 + quad * 8);
        acc[t] = __builtin_amdgcn_mfma_f32_16x16x32_bf16(af, bf, acc[t], 0, 0, 0);
      }
    }
  }

  int cob = cotile * 64 + wave * 16 + quad * 4;
#pragma unroll
  for (int i = 0; i < 4; ++i) {
    float bv = bias[cob + i];
#pragma unroll
    for (int t = 0; t < 8; ++t) {
      int y = y0 + (t >> 1), xc = (t & 1) * 16 + m16;
      out[((size_t)(b * 512) + cob + i) * 1024 + y * 32 + xc] = acc[t][i] + bv;
    }
  }
}

// ---------------------------------------------------------------------------
// K2: qkv 1x1 conv as MFMA GEMM 768 x 1024 x 256 per batch.
// Block: 64 c x 128 l. grid (8 ltile, 12 ctile, 8 b).
// R7: register prefetch of next K-chunk's A (4x float4) + B (4x uint4).
// Epilogue: per-wave LDS transpose -> coalesced stores (q/k row-major, v d-major).
// ---------------------------------------------------------------------------
__global__ __launch_bounds__(256) void qkv_mfma_kernel(
    const bf16* __restrict__ xT, const float* __restrict__ wq, const float* __restrict__ bias,
    bf16* __restrict__ qT, bf16* __restrict__ kR, bf16* __restrict__ vW)
{
  __shared__ __align__(16) short smem[13824];
  short* aS = smem;            // [64][72]
  short* bS = smem + 4608;     // [128][72]

  int tid = threadIdx.x, lane = tid & 63, wave = tid >> 6;
  int m16 = lane & 15, quad = lane >> 4;
  int l0 = blockIdx.x * 128;
  int ctile = blockIdx.y;
  int b = blockIdx.z;
  int cbase = ctile * 64;

  // staging geometry (chunk-invariant)
  int ac[4], as4[4], bl[4], bseg[4];
#pragma unroll
  for (int r = 0; r < 4; ++r) {
    int u = r * 256 + tid;
    ac[r] = u >> 4;  as4[r] = u & 15;
    bl[r] = u >> 3;  bseg[r] = u & 7;
  }

  float4 areg[4]; uint4 breg[4];
#pragma unroll
  for (int r = 0; r < 4; ++r) {
    areg[r] = *(const float4*)(wq + (size_t)(cbase + ac[r]) * 256 + as4[r] * 4);
    breg[r] = *(const uint4*)(xT + ((size_t)(b * 1024) + l0 + bl[r]) * 256 + bseg[r] * 8);
  }

  f32x4 acc[8];
#pragma unroll
  for (int t = 0; t < 8; ++t) acc[t] = (f32x4){0.f, 0.f, 0.f, 0.f};

  for (int ck = 0; ck < 4; ++ck) {
    __syncthreads();
#pragma unroll
    for (int r = 0; r < 4; ++r) {
      float4 v = areg[r];
      unsigned int p0 = (unsigned int)f2bfbits(v.x) | ((unsigned int)f2bfbits(v.y) << 16);
      unsigned int p1 = (unsigned int)f2bfbits(v.z) | ((unsigned int)f2bfbits(v.w) << 16);
      uint2 u2; u2.x = p0; u2.y = p1;
      *(uint2*)(aS + ac[r] * 72 + as4[r] * 4) = u2;
      *(uint4*)(bS + bl[r] * 72 + bseg[r] * 8) = breg[r];
    }
    if (ck < 3) {
#pragma unroll
      for (int r = 0; r < 4; ++r) {
        areg[r] = *(const float4*)(wq + (size_t)(cbase + ac[r]) * 256 + (ck + 1) * 64 + as4[r] * 4);
        breg[r] = *(const uint4*)(xT + ((size_t)(b * 1024) + l0 + bl[r]) * 256 + (ck + 1) * 64 + bseg[r] * 8);
      }
    }
    __syncthreads();
#pragma unroll
    for (int ks = 0; ks < 2; ++ks) {
      bf16x8 af = *(const bf16x8*)(aS + (wave * 16 + m16) * 72 + ks * 32 + quad * 8);
#pragma unroll
      for (int t = 0; t < 8; ++t) {
        bf16x8 bf = *(const bf16x8*)(bS + (t * 16 + m16) * 72 + ks * 32 + quad * 8);
        acc[t] = __builtin_amdgcn_mfma_f32_16x16x32_bf16(af, bf, acc[t], 0, 0, 0);
      }
    }
  }

  __syncthreads();   // all waves done reading aS/bS; alias as transpose scratch
  short* ldsT = smem + wave * 3072;          // per-wave [128 l][24] (16 c used)
  int cb = cbase + wave * 16;
  bool isq = (ctile < 4);
  float bv[4];
#pragma unroll
  for (int i = 0; i < 4; ++i) bv[i] = bias[cb + quad * 4 + i];
#pragma unroll
  for (int t = 0; t < 8; ++t) {
#pragma unroll
    for (int i = 0; i < 4; ++i) {
      float v = acc[t][i] + bv[i];
      if (isq) v *= 0.17677669529663689f;    // 32^-0.5, pre-rel-logits
      ldsT[(t * 16 + m16) * 24 + quad * 4 + i] = (short)f2bfbits(v);
    }
  }
  // per-wave region, same-wave readback: compiler's lgkmcnt ordering suffices
  if (ctile < 8) {
    bf16* dst = isq ? qT : kR;
    int coff = isq ? cb : cb - 256;
#pragma unroll
    for (int rep = 0; rep < 4; ++rep) {
      int u = rep * 64 + lane;
      int l = u >> 1, half = u & 1;
      int c0 = coff + half * 8;
      int head = b * 8 + (c0 >> 5), d0 = c0 & 31;
      *(uint4*)(dst + ((size_t)head * 1024 + l0 + l) * 32 + d0) =
          *(const uint4*)(ldsT + l * 24 + half * 8);
    }
  } else {
    int dcol = lane >> 2, lg = lane & 3;
    int c2 = (cb - 512) + dcol;
    int head = b * 8 + (c2 >> 5), gd = c2 & 31;
#pragma unroll
    for (int s = 0; s < 4; ++s) {
      union { unsigned int w[4]; uint4 u4; } pk;
#pragma unroll
      for (int p = 0; p < 4; ++p) {
        int j0 = lg * 32 + s * 8 + p * 2;
        unsigned int u0 = (unsigned short)ldsT[j0 * 24 + dcol];
        unsigned int u1 = (unsigned short)ldsT[(j0 + 1) * 24 + dcol];
        pk.w[p] = u0 | (u1 << 16);
      }
      *(uint4*)(vW + ((size_t)head * 32 + gd) * 1024 + l0 + lg * 32 + s * 8) = pk.u4;
    }
  }
}

// ---------------------------------------------------------------------------
// K3: MFMA attention, augmented-K rel logits (unchanged from round 6).
// ---------------------------------------------------------------------------
__global__ __launch_bounds__(256) void attn_mfma_kernel(
    const bf16* __restrict__ qT, const bf16* __restrict__ kR, const bf16* __restrict__ vW,
    const float* __restrict__ krw, const float* __restrict__ krh,
    bf16* __restrict__ attL)
{
  __shared__ __align__(16) char smem[31232];
  short* kaugS  = (short*)smem;              // [64 key][104]: k(32)|RWoh(32)|RHoh(32)
  short* vtS    = (short*)(smem + 13312);    // [32 d][72]
  short* atileS = (short*)(smem + 17920);    // prologue Atile / loop pS
  float* krwS   = (float*)smem;              // prologue alias
  float* krhS   = krwS + 63 * 33;

  int tid = threadIdx.x;
  int lane = tid & 63, wave = tid >> 6;
  int m16 = lane & 15, quad = lane >> 4;
  int bid = blockIdx.x;
  // same head -> same blockIdx mod 8 -> same XCD (round-robin heuristic)
  int head = ((bid & 7) << 3) | ((bid >> 3) & 7);
  int qt = bid >> 6;
  int row0 = qt * 64;
  int b = head >> 3, h = head & 7;

  // staging roles + chunk-0 prefetch (issue early; prologue hides latency)
  int skey = tid >> 2, sseg = tid & 3;       // K: 64 keys x 4 segs of 8
  int svd = tid >> 3, svk = tid & 7;         // V: 32 d x 8 key-segs of 8
  const bf16* kptr = kR + (size_t)head * 32768 + skey * 32 + sseg * 8;
  const bf16* vptr = vW + (size_t)head * 32768 + svd * 1024 + svk * 8;
  uint4 kreg = *(const uint4*)kptr;
  uint4 vreg = *(const uint4*)vptr;

  // ---- phase 0: stage krw/krh (padded x33) and q rows into Atile ----
  for (int i = tid; i < 504; i += 256) {
    int row = i >> 3, d0 = (i & 7) * 4;
    float4 a = *(const float4*)(krw + row * 32 + d0);
    krwS[row * 33 + d0 + 0] = a.x; krwS[row * 33 + d0 + 1] = a.y;
    krwS[row * 33 + d0 + 2] = a.z; krwS[row * 33 + d0 + 3] = a.w;
    float4 c = *(const float4*)(krh + row * 32 + d0);
    krhS[row * 33 + d0 + 0] = c.x; krhS[row * 33 + d0 + 1] = c.y;
    krhS[row * 33 + d0 + 2] = c.z; krhS[row * 33 + d0 + 3] = c.w;
  }
  {
    int r = tid >> 2, seg = tid & 3;
    uint4 u = *(const uint4*)(qT + ((size_t)head * 1024 + row0 + r) * 32 + seg * 8);
    *(uint4*)(atileS + r * 104 + seg * 8) = u;
  }
  __syncthreads();

  // ---- phase 1: RW/RH tables -> Atile[.][32..96) ----
  {
    int r = tid >> 2, jseg = tid & 3;
    int qi = r & 31;
    int qx = qt * 2 + (r >> 5);
    float q32[32];
#pragma unroll
    for (int s4 = 0; s4 < 4; ++s4) {
      uint4 u = ((const uint4*)(atileS + r * 104))[s4];
      q32[s4 * 8 + 0] = blo(u.x); q32[s4 * 8 + 1] = bhi(u.x);
      q32[s4 * 8 + 2] = blo(u.y); q32[s4 * 8 + 3] = bhi(u.y);
      q32[s4 * 8 + 4] = blo(u.z); q32[s4 * 8 + 5] = bhi(u.z);
      q32[s4 * 8 + 6] = blo(u.w); q32[s4 * 8 + 7] = bhi(u.w);
    }
    unsigned int pw[4], ph[4];
#pragma unroll
    for (int jp = 0; jp < 4; ++jp) {
      float sv[4] = {0.f, 0.f, 0.f, 0.f};
#pragma unroll 2
      for (int half = 0; half < 2; ++half) {
        int j = jseg * 8 + jp * 2 + half;
        const float* kw = krwS + (j - qi + 31) * 33;
        const float* kh = krhS + (j - qx + 31) * 33;
        float s1 = 0.f, s2 = 0.f;
#pragma unroll
        for (int d = 0; d < 32; ++d) { s1 += q32[d] * kw[d]; s2 += q32[d] * kh[d]; }
        sv[half] = s1; sv[2 + half] = s2;
      }
      pw[jp] = (unsigned int)(unsigned short)f2bfr(sv[0]) |
               ((unsigned int)(unsigned short)f2bfr(sv[1]) << 16);
      ph[jp] = (unsigned int)(unsigned short)f2bfr(sv[2]) |
               ((unsigned int)(unsigned short)f2bfr(sv[3]) << 16);
    }
#pragma unroll
    for (int jp = 0; jp < 4; ++jp) {
      ((unsigned int*)(atileS + r * 104 + 32 + jseg * 8))[jp] = pw[jp];
      ((unsigned int*)(atileS + r * 104 + 64 + jseg * 8))[jp] = ph[jp];
    }
  }
  __syncthreads();   // phase1 reads of krwS/krhS done; kaugS region now free

  // ---- one-hot init (once): zero [32,96), set RW one at 32+(key&31) ----
  {
    union { short s[16]; uint4 u4[2]; } oh;
#pragma unroll
    for (int e = 0; e < 16; ++e) oh.s[e] = 0;
    int base = 32 + sseg * 16;
    int pos = 32 + (skey & 31);
    if (pos >= base && pos < base + 16) oh.s[pos - base] = (short)0x3F80;
    ((uint4*)(kaugS + skey * 104 + 32 + sseg * 16))[0] = oh.u4[0];
    *((uint4*)(kaugS + skey * 104 + 32 + sseg * 16) + 1) = oh.u4[1];
  }

  // ---- persistent A-frags (q | RW | RH) ----
  bf16x8 afrag[3];
  {
    int arow = wave * 16 + m16;
#pragma unroll
    for (int ks = 0; ks < 3; ++ks)
      afrag[ks] = *(const bf16x8*)(atileS + arow * 104 + ks * 32 + quad * 8);
  }

  // ---- K-loop over 16 chunks of 64 keys, register-prefetched ----
  f32x4 oacc[2];
  oacc[0] = (f32x4){0.f, 0.f, 0.f, 0.f};
  oacc[1] = (f32x4){0.f, 0.f, 0.f, 0.f};
  float rsp[4] = {0.f, 0.f, 0.f, 0.f};
  short* pS = (short*)(smem + 17920) + wave * 1152;   // [16 q][72 key-padded]

  for (int c = 0; c < 16; ++c) {
    __syncthreads();                          // prev compute done reading LDS
    *(uint4*)(kaugS + skey * 104 + sseg * 8) = kreg;
    if (sseg == 0) {                          // RH one-hot shift (+2 per chunk)
      if (c) kaugS[skey * 104 + 64 + (c - 1) * 2 + (skey >> 5)] = 0;
      kaugS[skey * 104 + 64 + c * 2 + (skey >> 5)] = (short)0x3F80;
    }
    *(uint4*)(vtS + svd * 72 + svk * 8) = vreg;
    if (c < 15) {                             // prefetch next chunk (latency
      kreg = *(const uint4*)(kptr + (c + 1) * 2048);  //  overlaps compute below)
      vreg = *(const uint4*)(vptr + (c + 1) * 64);
    }
    __syncthreads();                          // staging visible

    // QK^T (augmented K-dim 96): 4 n-tiles x 3 k-steps
    f32x4 sacc[4];
#pragma unroll
    for (int t = 0; t < 4; ++t) sacc[t] = (f32x4){0.f, 0.f, 0.f, 0.f};
#pragma unroll
    for (int t = 0; t < 4; ++t) {
#pragma unroll
      for (int ks = 0; ks < 3; ++ks) {
        bf16x8 bfK = *(const bf16x8*)(kaugS + (t * 16 + m16) * 104 + ks * 32 + quad * 8);
        sacc[t] = __builtin_amdgcn_mfma_f32_16x16x32_bf16(afrag[ks], bfK, sacc[t], 0, 0, 0);
      }
    }
    // exp (no max-sub: logits bounded), row-sum partials, P -> LDS (C/D->A)
#pragma unroll
    for (int t = 0; t < 4; ++t) {
#pragma unroll
      for (int i = 0; i < 4; ++i) {
        float e = __expf(sacc[t][i]);
        rsp[i] += e;
        pS[(quad * 4 + i) * 72 + t * 16 + m16] = f2bfr(e);
      }
    }
    // PV: 2 k-steps (32 keys) x 2 d-tiles
#pragma unroll
    for (int ks2 = 0; ks2 < 2; ++ks2) {
      bf16x8 pf = *(const bf16x8*)(pS + m16 * 72 + ks2 * 32 + quad * 8);
#pragma unroll
      for (int dt = 0; dt < 2; ++dt) {
        bf16x8 vf = *(const bf16x8*)(vtS + (dt * 16 + m16) * 72 + ks2 * 32 + quad * 8);
        oacc[dt] = __builtin_amdgcn_mfma_f32_16x16x32_bf16(pf, vf, oacc[dt], 0, 0, 0);
      }
    }
  }

  // ---- epilogue: reduce row-sums within quad, normalize, store ----
#pragma unroll
  for (int off = 1; off < 16; off <<= 1)
#pragma unroll
    for (int i = 0; i < 4; ++i) rsp[i] += __shfl_xor(rsp[i], off, 64);
#pragma unroll
  for (int i = 0; i < 4; ++i) {
    float invs = 1.0f / rsp[i];
    int grow = row0 + wave * 16 + quad * 4 + i;
#pragma unroll
    for (int dt = 0; dt < 2; ++dt) {
      attL[((size_t)b * 1024 + grow) * 256 + h * 32 + dt * 16 + m16] =
          __float2bfloat16(oacc[dt][i] * invs);
    }
  }
}

// ---------------------------------------------------------------------------
// K4: attnout 1x1 conv as MFMA GEMM 256 x 1024 x 256 per batch.
// Block: 64 co x 128 l. grid (8 ltile, 4 cotile, 8 b) = 256 blocks.
// R7: register prefetch of next K-chunk's A (4x float4) + B (4x uint4).
// Epilogue: direct fp32 stores, C/D-layout -> 64B-contiguous runs along l.
// ---------------------------------------------------------------------------
__global__ __launch_bounds__(256) void attnout_mfma_kernel(
    const bf16* __restrict__ attL, const float* __restrict__ w, const float* __restrict__ bias,
    float* __restrict__ out)
{
  __shared__ __align__(16) short smem[13824];
  short* aS = smem;            // [64 co][72]
  short* bS = smem + 4608;     // [128 l][72]

  int tid = threadIdx.x, lane = tid & 63, wave = tid >> 6;
  int m16 = lane & 15, quad = lane >> 4;
  int l0 = blockIdx.x * 128;
  int cotile = blockIdx.y;
  int b = blockIdx.z;
  int cbase = cotile * 64;

  int ac[4], as4[4], bl[4], bseg[4];
#pragma unroll
  for (int r = 0; r < 4; ++r) {
    int u = r * 256 + tid;
    ac[r] = u >> 4;  as4[r] = u & 15;
    bl[r] = u >> 3;  bseg[r] = u & 7;
  }

  float4 areg[4]; uint4 breg[4];
#pragma unroll
  for (int r = 0; r < 4; ++r) {
    areg[r] = *(const float4*)(w + (size_t)(cbase + ac[r]) * 256 + as4[r] * 4);
    breg[r] = *(const uint4*)(attL + ((size_t)(b * 1024) + l0 + bl[r]) * 256 + bseg[r] * 8);
  }

  f32x4 acc[8];
#pragma unroll
  for (int t = 0; t < 8; ++t) acc[t] = (f32x4){0.f, 0.f, 0.f, 0.f};

  for (int ck = 0; ck < 4; ++ck) {
    __syncthreads();
#pragma unroll
    for (int r = 0; r < 4; ++r) {
      float4 v = areg[r];
      unsigned int p0 = (unsigned int)f2bfbits(v.x) | ((unsigned int)f2bfbits(v.y) << 16);
      unsigned int p1 = (unsigned int)f2bfbits(v.z) | ((unsigned int)f2bfbits(v.w) << 16);
      uint2 u2; u2.x = p0; u2.y = p1;
      *(uint2*)(aS + ac[r] * 72 + as4[r] * 4) = u2;
      *(uint4*)(bS + bl[r] * 72 + bseg[r] * 8) = breg[r];
    }
    if (ck < 3) {
#pragma unroll
      for (int r = 0; r < 4; ++r) {
        areg[r] = *(const float4*)(w + (size_t)(cbase + ac[r]) * 256 + (ck + 1) * 64 + as4[r] * 4);
        breg[r] = *(const uint4*)(attL + ((size_t)(b * 1024) + l0 + bl[r]) * 256 + (ck + 1) * 64 + bseg[r] * 8);
      }
    }
    __syncthreads();
#pragma unroll
    for (int ks = 0; ks < 2; ++ks) {
      bf16x8 af = *(const bf16x8*)(aS + (wave * 16 + m16) * 72 + ks * 32 + quad * 8);
#pragma unroll
      for (int t = 0; t < 8; ++t) {
        bf16x8 bf = *(const bf16x8*)(bS + (t * 16 + m16) * 72 + ks * 32 + quad * 8);
        acc[t] = __builtin_amdgcn_mfma_f32_16x16x32_bf16(af, bf, acc[t], 0, 0, 0);
      }
    }
  }

  int co = cbase + wave * 16 + quad * 4;
#pragma unroll
  for (int i = 0; i < 4; ++i) {
    float bv = bias[co + i];
    size_t obase = ((size_t)(b * 512) + 256 + co + i) * 1024 + l0;
#pragma unroll
    for (int t = 0; t < 8; ++t)
      out[obase + t * 16 + m16] = acc[t][i] + bv;
  }
}

// ---------------------------------------------------------------------------
extern "C" void kernel_launch(void* const* d_in, const int* in_sizes, int n_in,
                              void* d_out, int out_size, void* d_ws, size_t ws_size,
                              hipStream_t stream) {
  const float* x      = (const float*)d_in[0];
  const float* w_qkv  = (const float*)d_in[1];
  const float* b_qkv  = (const float*)d_in[2];
  const float* w_attn = (const float*)d_in[3];
  const float* b_attn = (const float*)d_in[4];
  const float* w_out  = (const float*)d_in[5];
  const float* b_out  = (const float*)d_in[6];
  const float* krw    = (const float*)d_in[7];
  const float* krh    = (const float*)d_in[8];
  float* out = (float*)d_out;

  bf16* ws    = (bf16*)d_ws;
  bf16* xT    = ws;                 // [0, 2,097,152)   dead after qkv
  bf16* attL  = ws;                 // alias of xT      (attn -> attnout)
  bf16* wo_bf = ws + 2097152;       // [2,097,152, 2,686,976)  dead after conv3
  bf16* qT    = ws + 2097152;       // [2,097,152, 4,194,304)  written after conv3
  bf16* kR    = ws + 4194304;       // [4,194,304, 6,291,456)
  bf16* vW    = ws + 6291456;       // [6,291,456, 8,388,608)  exact 16 MB fit

  prep_kernel<<<dim3(2084), 256, 0, stream>>>(x, w_out, xT, wo_bf);
  conv3_mfma_kernel<<<dim3(256), 256, 0, stream>>>(xT, wo_bf, b_out, out);
  qkv_mfma_kernel<<<dim3(8, 12, 8), 256, 0, stream>>>(xT, w_qkv, b_qkv, qT, kR, vW);
  attn_mfma_kernel<<<dim3(1024), 256, 0, stream>>>(qT, kR, vW, krw, krh, attL);
  attnout_mfma_kernel<<<dim3(8, 4, 8), 256, 0, stream>>>(attL, w_attn, b_attn, out);
}

// Round 9
// 181.625 us; speedup vs baseline: 1.1385x; 1.1385x over previous
//
#include <hip/hip_runtime.h>
#include <hip/hip_bf16.h>

// AttentionConv2d: B=8, C_IN=256, H=W=32 (HW=1024), DK=DV=256, NH=8, DKH=DVH=32,
// C_OUT=512, 3x3 conv pad=1. fp32 storage in/out; bf16 intermediates + MFMA.
//
// Workspace (bf16 elements, EXACTLY 16 MB = 8,388,608 bf16 — proven safe size):
//   xT    [8 b][1024 l][256 ci]  @ 0          (dead after qkv)  } aliased later by
//   attL  [8 b][1024 l][256 ch]  @ 0          (attn -> attnout) } each other
//   wo_bf chunk-blocked          @ 2,097,152  (589,824; dead after conv3)
//   qT    [64 head][1024][32]    @ 2,097,152  (written by qkv AFTER conv3 -> safe alias)
//   kR    [64 head][1024][32]    @ 4,194,304
//   vW    [64 head][32][1024]    @ 6,291,456  (ends exactly 8,388,608)
// Kernel order: prep -> conv3 -> qkv -> attn -> attnout (stream-serial).
// R9 = R8 with the uint4->bf16x8 casts fixed (direct bf16x8 loads).

typedef __hip_bfloat16 bf16;
typedef __attribute__((ext_vector_type(8))) short bf16x8;
typedef __attribute__((ext_vector_type(4))) float f32x4;

__device__ __forceinline__ float bf2f(bf16 v) { return __bfloat162float(v); }
__device__ __forceinline__ float blo(unsigned int v) { return __uint_as_float(v << 16); }
__device__ __forceinline__ float bhi(unsigned int v) { return __uint_as_float(v & 0xffff0000u); }
__device__ __forceinline__ unsigned short f2bfbits(float f) {
  union { bf16 h; unsigned short u; } cv; cv.h = __float2bfloat16(f); return cv.u;
}
// cheap round-to-nearest (ties away): 2 VALU ops vs ~4 for RNE; <=1 ulp diff.
__device__ __forceinline__ short f2bfr(float f) {
  return (short)((__float_as_uint(f) + 0x8000u) >> 16);
}
// B-operand one-hot fragment for a 32-dim K-group: element `elem` (0..31) = 1.0.
// Lane (m16,quad) holds kdims quad*8..quad*8+7; active lane: quad==elem>>3,
// halfword elem&7 -> word (elem>>1)&3, half elem&1.
__device__ __forceinline__ bf16x8 onehot_frag(int elem, int quad) {
  union { unsigned int w[4]; bf16x8 v; } f;
  unsigned int val = (elem & 1) ? 0x3F800000u : 0x00003F80u;
  int sel = (elem >> 1) & 3;
  bool act = (quad == (elem >> 3));
#pragma unroll
  for (int i = 0; i < 4; ++i) f.w[i] = (act && sel == i) ? val : 0u;
  return f.v;
}

// ---------------------------------------------------------------------------
// K0: prep — xT transpose to bf16 + w_out bf16 chunk-blocked.
// blocks 0..2047: xT; 2048..2083: w_out. grid 2084.
// ---------------------------------------------------------------------------
__global__ __launch_bounds__(256) void prep_kernel(
    const float* __restrict__ x, const float* __restrict__ wout,
    bf16* __restrict__ xT, bf16* __restrict__ wo_bf)
{
  int bid = blockIdx.x, tid = threadIdx.x;
  if (bid < 2048) {
    __shared__ float t[32 * 33];
    int b = bid >> 8, rem = bid & 255;
    int ci0 = (rem >> 5) * 32, l0 = (rem & 31) * 32;
    {
      int ciL = tid >> 3, lL4 = (tid & 7) * 4;
      float4 v = *(const float4*)(x + (size_t)(b * 256 + ci0 + ciL) * 1024 + l0 + lL4);
      t[ciL * 33 + lL4 + 0] = v.x; t[ciL * 33 + lL4 + 1] = v.y;
      t[ciL * 33 + lL4 + 2] = v.z; t[ciL * 33 + lL4 + 3] = v.w;
    }
    __syncthreads();
    {
      int lL = tid >> 3, cS = (tid & 7) * 4;
      unsigned int p0 = (unsigned int)f2bfbits(t[(cS + 0) * 33 + lL]) |
                        ((unsigned int)f2bfbits(t[(cS + 1) * 33 + lL]) << 16);
      unsigned int p1 = (unsigned int)f2bfbits(t[(cS + 2) * 33 + lL]) |
                        ((unsigned int)f2bfbits(t[(cS + 3) * 33 + lL]) << 16);
      uint2 u2; u2.x = p0; u2.y = p1;
      *(uint2*)(xT + ((size_t)(b * 1024) + l0 + lL) * 256 + ci0 + cS) = u2;
    }
  } else {
    int t0 = (bid - 2048) * 256 + tid;       // 0..9215
#pragma unroll
    for (int s = 0; s < 8; ++s) {
      int u = s * 9216 + t0;                 // dst uint4 index 0..73727
      int chunkblk = u / 2304;
      int within = u - chunkblk * 2304;
      int co63 = within / 36;
      int r = within - co63 * 36;            // kidx*4 + cig
      int kidx = r >> 2, cig = r & 3;
      int co = (chunkblk >> 3) * 64 + co63;
      int ci = (chunkblk & 7) * 32 + cig * 8;
      union { unsigned short h[8]; uint4 u4; } pk;
#pragma unroll
      for (int j = 0; j < 8; ++j)
        pk.h[j] = f2bfbits(wout[(size_t)(co * 256 + ci + j) * 9 + kidx]);
      *(uint4*)(wo_bf + (size_t)u * 8) = pk.u4;
    }
  }
}

// ---------------------------------------------------------------------------
// K1: 3x3 conv 256->256 via 9 shift-GEMMs, MFMA bf16. (R6 version)
// ---------------------------------------------------------------------------
__global__ __launch_bounds__(256) void conv3_mfma_kernel(
    const bf16* __restrict__ xT, const bf16* __restrict__ wo_bf,
    const float* __restrict__ bias, float* __restrict__ out)
{
  __shared__ __align__(16) short smem[27104];
  short* wS = smem;            // 64*296 = 18944
  short* xS = smem + 18944;    // 6*34*40 = 8160

  int tid = threadIdx.x, lane = tid & 63, wave = tid >> 6;
  int m16 = lane & 15, quad = lane >> 4;
  int bid = blockIdx.x;
  int rc = bid & 7, cotile = (bid >> 3) & 3, b = bid >> 5;
  int y0 = rc * 4;

  f32x4 acc[8];
#pragma unroll
  for (int t = 0; t < 8; ++t) acc[t] = (f32x4){0.f, 0.f, 0.f, 0.f};

  for (int ck = 0; ck < 8; ++ck) {
    __syncthreads();
    const bf16* wbase = wo_bf + (size_t)(cotile * 8 + ck) * 18432;
#pragma unroll
    for (int r = 0; r < 9; ++r) {            // 2304 uint4 units
      int u = r * 256 + tid;
      *(uint4*)(wS + (u / 36) * 296 + (u % 36) * 8) = *(const uint4*)(wbase + (size_t)u * 8);
    }
#pragma unroll
    for (int r = 0; r < 3; ++r) {            // 768 units: 6 rows x 32 cols x 4 segs
      int u = r * 256 + tid;
      int pos = u >> 2, seg = u & 3;
      int row = pos >> 5, col = pos & 31;
      int gy = y0 - 1 + row;
      uint4 val = make_uint4(0u, 0u, 0u, 0u);
      if (gy >= 0 && gy < 32)
        val = *(const uint4*)(xT + ((size_t)(b * 1024) + gy * 32 + col) * 256 + ck * 32 + seg * 8);
      *(uint4*)(xS + (row * 34 + col + 1) * 40 + seg * 8) = val;
    }
    if (tid < 48) {                           // zero halo cols (x=-1 and x=32)
      int pos = tid >> 2, seg = tid & 3;
      int row = pos >> 1, side = pos & 1;
      *(uint4*)(xS + (row * 34 + side * 33) * 40 + seg * 8) = make_uint4(0u, 0u, 0u, 0u);
    }
    __syncthreads();
#pragma unroll
    for (int kidx = 0; kidx < 9; ++kidx) {
      int dy = kidx / 3, dx = kidx - dy * 3;
      bf16x8 af = *(const bf16x8*)(wS + (wave * 16 + m16) * 296 + kidx * 32 + quad * 8);
#pragma unroll
      for (int t = 0; t < 8; ++t) {
        int row = (t >> 1) + dy;
        int col = (t & 1) * 16 + m16 + dx;
        bf16x8 bf = *(const bf16x8*)(xS + (row * 34 + col) * 40 + quad * 8);
        acc[t] = __builtin_amdgcn_mfma_f32_16x16x32_bf16(af, bf, acc[t], 0, 0, 0);
      }
    }
  }

  int cob = cotile * 64 + wave * 16 + quad * 4;
#pragma unroll
  for (int i = 0; i < 4; ++i) {
    float bv = bias[cob + i];
#pragma unroll
    for (int t = 0; t < 8; ++t) {
      int y = y0 + (t >> 1), xc = (t & 1) * 16 + m16;
      out[((size_t)(b * 512) + cob + i) * 1024 + y * 32 + xc] = acc[t][i] + bv;
    }
  }
}

// ---------------------------------------------------------------------------
// K2: qkv 1x1 conv as MFMA GEMM 768 x 1024 x 256 per batch. (R6 version)
// ---------------------------------------------------------------------------
__global__ __launch_bounds__(256) void qkv_mfma_kernel(
    const bf16* __restrict__ xT, const float* __restrict__ wq, const float* __restrict__ bias,
    bf16* __restrict__ qT, bf16* __restrict__ kR, bf16* __restrict__ vW)
{
  __shared__ __align__(16) short smem[13824];
  short* aS = smem;            // [64][72]
  short* bS = smem + 4608;     // [128][72]

  int tid = threadIdx.x, lane = tid & 63, wave = tid >> 6;
  int m16 = lane & 15, quad = lane >> 4;
  int l0 = blockIdx.x * 128;
  int ctile = blockIdx.y;
  int b = blockIdx.z;
  int cbase = ctile * 64;

  f32x4 acc[8];
#pragma unroll
  for (int t = 0; t < 8; ++t) acc[t] = (f32x4){0.f, 0.f, 0.f, 0.f};

  for (int ck = 0; ck < 4; ++ck) {
    __syncthreads();
#pragma unroll
    for (int r = 0; r < 4; ++r) {            // A: 64 c x 64 ci from f32, cvt
      int u = r * 256 + tid;                  // 1024 float4 units
      int c = u >> 4, s4 = u & 15;
      float4 v = *(const float4*)(wq + (size_t)(cbase + c) * 256 + ck * 64 + s4 * 4);
      unsigned int p0 = (unsigned int)f2bfbits(v.x) | ((unsigned int)f2bfbits(v.y) << 16);
      unsigned int p1 = (unsigned int)f2bfbits(v.z) | ((unsigned int)f2bfbits(v.w) << 16);
      uint2 u2; u2.x = p0; u2.y = p1;
      *(uint2*)(aS + c * 72 + s4 * 4) = u2;
    }
#pragma unroll
    for (int r = 0; r < 4; ++r) {            // B: 128 l x 64 ci bf16
      int u = r * 256 + tid;                  // 1024 uint4 units
      int l = u >> 3, seg = u & 7;
      *(uint4*)(bS + l * 72 + seg * 8) =
          *(const uint4*)(xT + ((size_t)(b * 1024) + l0 + l) * 256 + ck * 64 + seg * 8);
    }
    __syncthreads();
#pragma unroll
    for (int ks = 0; ks < 2; ++ks) {
      bf16x8 af = *(const bf16x8*)(aS + (wave * 16 + m16) * 72 + ks * 32 + quad * 8);
#pragma unroll
      for (int t = 0; t < 8; ++t) {
        bf16x8 bf = *(const bf16x8*)(bS + (t * 16 + m16) * 72 + ks * 32 + quad * 8);
        acc[t] = __builtin_amdgcn_mfma_f32_16x16x32_bf16(af, bf, acc[t], 0, 0, 0);
      }
    }
  }

  __syncthreads();   // all waves done reading aS/bS; alias as transpose scratch
  short* ldsT = smem + wave * 3072;          // per-wave [128 l][24] (16 c used)
  int cb = cbase + wave * 16;
  bool isq = (ctile < 4);
  float bv[4];
#pragma unroll
  for (int i = 0; i < 4; ++i) bv[i] = bias[cb + quad * 4 + i];
#pragma unroll
  for (int t = 0; t < 8; ++t) {
#pragma unroll
    for (int i = 0; i < 4; ++i) {
      float v = acc[t][i] + bv[i];
      if (isq) v *= 0.17677669529663689f;    // 32^-0.5, pre-rel-logits
      ldsT[(t * 16 + m16) * 24 + quad * 4 + i] = (short)f2bfbits(v);
    }
  }
  // per-wave region, same-wave readback: compiler's lgkmcnt ordering suffices
  if (ctile < 8) {
    bf16* dst = isq ? qT : kR;
    int coff = isq ? cb : cb - 256;
#pragma unroll
    for (int rep = 0; rep < 4; ++rep) {
      int u = rep * 64 + lane;
      int l = u >> 1, half = u & 1;
      int c0 = coff + half * 8;
      int head = b * 8 + (c0 >> 5), d0 = c0 & 31;
      *(uint4*)(dst + ((size_t)head * 1024 + l0 + l) * 32 + d0) =
          *(const uint4*)(ldsT + l * 24 + half * 8);
    }
  } else {
    int dcol = lane >> 2, lg = lane & 3;
    int c2 = (cb - 512) + dcol;
    int head = b * 8 + (c2 >> 5), gd = c2 & 31;
#pragma unroll
    for (int s = 0; s < 4; ++s) {
      union { unsigned int w[4]; uint4 u4; } pk;
#pragma unroll
      for (int p = 0; p < 4; ++p) {
        int j0 = lg * 32 + s * 8 + p * 2;
        unsigned int u0 = (unsigned short)ldsT[j0 * 24 + dcol];
        unsigned int u1 = (unsigned short)ldsT[(j0 + 1) * 24 + dcol];
        pk.w[p] = u0 | (u1 << 16);
      }
      *(uint4*)(vW + ((size_t)head * 32 + gd) * 1024 + l0 + lg * 32 + s * 8) = pk.u4;
    }
  }
}

// ---------------------------------------------------------------------------
// K3: MFMA attention, augmented-K rel logits. Barrier-free K-loop —
// K and V B-frags loaded straight from global (layouts match MFMA B-frag),
// one-hot rel B-frags synthesized in registers (RW chunk-invariant,
// RH = onehot(2c+tt)). LDS only for prologue tables + per-wave P roundtrip.
// ---------------------------------------------------------------------------
__global__ __launch_bounds__(256) void attn_mfma_kernel(
    const bf16* __restrict__ qT, const bf16* __restrict__ kR, const bf16* __restrict__ vW,
    const float* __restrict__ krw, const float* __restrict__ krh,
    bf16* __restrict__ attL)
{
  __shared__ __align__(16) char smem[31232];
  short* atileS = (short*)(smem + 17920);    // prologue Atile / loop pS
  float* krwS   = (float*)smem;              // prologue alias (0..16632)
  float* krhS   = krwS + 63 * 33;

  int tid = threadIdx.x;
  int lane = tid & 63, wave = tid >> 6;
  int m16 = lane & 15, quad = lane >> 4;
  int bid = blockIdx.x;
  // same head -> same blockIdx mod 8 -> same XCD (round-robin heuristic)
  int head = ((bid & 7) << 3) | ((bid >> 3) & 7);
  int qt = bid >> 6;
  int row0 = qt * 64;
  int b = head >> 3, h = head & 7;

  // ---- phase 0: stage krw/krh (padded x33) and q rows into Atile ----
  for (int i = tid; i < 504; i += 256) {
    int row = i >> 3, d0 = (i & 7) * 4;
    float4 a = *(const float4*)(krw + row * 32 + d0);
    krwS[row * 33 + d0 + 0] = a.x; krwS[row * 33 + d0 + 1] = a.y;
    krwS[row * 33 + d0 + 2] = a.z; krwS[row * 33 + d0 + 3] = a.w;
    float4 c = *(const float4*)(krh + row * 32 + d0);
    krhS[row * 33 + d0 + 0] = c.x; krhS[row * 33 + d0 + 1] = c.y;
    krhS[row * 33 + d0 + 2] = c.z; krhS[row * 33 + d0 + 3] = c.w;
  }
  {
    int r = tid >> 2, seg = tid & 3;
    uint4 u = *(const uint4*)(qT + ((size_t)head * 1024 + row0 + r) * 32 + seg * 8);
    *(uint4*)(atileS + r * 104 + seg * 8) = u;
  }
  __syncthreads();

  // ---- phase 1: RW/RH tables -> Atile[.][32..96) ----
  {
    int r = tid >> 2, jseg = tid & 3;
    int qi = r & 31;
    int qx = qt * 2 + (r >> 5);
    float q32[32];
#pragma unroll
    for (int s4 = 0; s4 < 4; ++s4) {
      uint4 u = ((const uint4*)(atileS + r * 104))[s4];
      q32[s4 * 8 + 0] = blo(u.x); q32[s4 * 8 + 1] = bhi(u.x);
      q32[s4 * 8 + 2] = blo(u.y); q32[s4 * 8 + 3] = bhi(u.y);
      q32[s4 * 8 + 4] = blo(u.z); q32[s4 * 8 + 5] = bhi(u.z);
      q32[s4 * 8 + 6] = blo(u.w); q32[s4 * 8 + 7] = bhi(u.w);
    }
    unsigned int pw[4], ph[4];
#pragma unroll
    for (int jp = 0; jp < 4; ++jp) {
      float sv[4] = {0.f, 0.f, 0.f, 0.f};
#pragma unroll 2
      for (int half = 0; half < 2; ++half) {
        int j = jseg * 8 + jp * 2 + half;
        const float* kw = krwS + (j - qi + 31) * 33;
        const float* kh = krhS + (j - qx + 31) * 33;
        float s1 = 0.f, s2 = 0.f;
#pragma unroll
        for (int d = 0; d < 32; ++d) { s1 += q32[d] * kw[d]; s2 += q32[d] * kh[d]; }
        sv[half] = s1; sv[2 + half] = s2;
      }
      pw[jp] = (unsigned int)(unsigned short)f2bfr(sv[0]) |
               ((unsigned int)(unsigned short)f2bfr(sv[1]) << 16);
      ph[jp] = (unsigned int)(unsigned short)f2bfr(sv[2]) |
               ((unsigned int)(unsigned short)f2bfr(sv[3]) << 16);
    }
#pragma unroll
    for (int jp = 0; jp < 4; ++jp) {
      ((unsigned int*)(atileS + r * 104 + 32 + jseg * 8))[jp] = pw[jp];
      ((unsigned int*)(atileS + r * 104 + 64 + jseg * 8))[jp] = ph[jp];
    }
  }
  __syncthreads();

  // ---- persistent A-frags (q | RW | RH) ----
  bf16x8 afrag[3];
  {
    int arow = wave * 16 + m16;
#pragma unroll
    for (int ks = 0; ks < 3; ++ks)
      afrag[ks] = *(const bf16x8*)(atileS + arow * 104 + ks * 32 + quad * 8);
  }
  __syncthreads();   // all afrags read; atileS region now safe to alias as pS

  // ---- RW one-hot B-frags (chunk-invariant): elem = m16 + 16*(t&1) ----
  bf16x8 rwfrag[2];
#pragma unroll
  for (int par = 0; par < 2; ++par)
    rwfrag[par] = onehot_frag(m16 + 16 * par, quad);

  // ---- K/V global B-frag pointers (direct MFMA-layout loads) ----
  const bf16* klane = kR + (size_t)head * 32768 + m16 * 32 + quad * 8;   // + c*2048 + t*512
  const bf16* vlane = vW + (size_t)head * 32768 + m16 * 1024 + quad * 8; // + dt*16384 + c*64 + ks2*32
  bf16x8 kcur[4];
#pragma unroll
  for (int t = 0; t < 4; ++t) kcur[t] = *(const bf16x8*)(klane + t * 512);

  f32x4 oacc[2];
  oacc[0] = (f32x4){0.f, 0.f, 0.f, 0.f};
  oacc[1] = (f32x4){0.f, 0.f, 0.f, 0.f};
  float rsp[4] = {0.f, 0.f, 0.f, 0.f};
  short* pS = (short*)(smem + 17920) + wave * 1152;   // per-wave [16 q][72 key-padded]

  for (int c = 0; c < 16; ++c) {
    // V frags for this chunk (consumed at end — latency hidden by QK+exp)
    bf16x8 vld[4];
#pragma unroll
    for (int ks2 = 0; ks2 < 2; ++ks2)
#pragma unroll
      for (int dt = 0; dt < 2; ++dt)
        vld[ks2 * 2 + dt] = *(const bf16x8*)(vlane + dt * 16384 + c * 64 + ks2 * 32);
    // RH one-hot frags: elem = 2c + tt (wave-uniform)
    bf16x8 rhfrag[2];
    rhfrag[0] = onehot_frag(2 * c + 0, quad);
    rhfrag[1] = onehot_frag(2 * c + 1, quad);

    // QK^T: 4 n-tiles x (k | RW-onehot | RH-onehot)
    f32x4 sacc[4];
#pragma unroll
    for (int t = 0; t < 4; ++t) {
      f32x4 s = (f32x4){0.f, 0.f, 0.f, 0.f};
      s = __builtin_amdgcn_mfma_f32_16x16x32_bf16(afrag[0], kcur[t], s, 0, 0, 0);
      s = __builtin_amdgcn_mfma_f32_16x16x32_bf16(afrag[1], rwfrag[t & 1], s, 0, 0, 0);
      s = __builtin_amdgcn_mfma_f32_16x16x32_bf16(afrag[2], rhfrag[t >> 1], s, 0, 0, 0);
      sacc[t] = s;
    }
    // prefetch next chunk's K frags (overlaps exp/PV below)
    if (c < 15) {
#pragma unroll
      for (int t = 0; t < 4; ++t)
        kcur[t] = *(const bf16x8*)(klane + (c + 1) * 2048 + t * 512);
    }
    // exp (no max-sub: logits bounded), row-sum partials, P -> LDS (C/D->A)
#pragma unroll
    for (int t = 0; t < 4; ++t) {
#pragma unroll
      for (int i = 0; i < 4; ++i) {
        float e = __expf(sacc[t][i]);
        rsp[i] += e;
        pS[(quad * 4 + i) * 72 + t * 16 + m16] = f2bfr(e);
      }
    }
    // PV: 2 k-steps (32 keys) x 2 d-tiles; same-wave LDS roundtrip (lgkmcnt only)
#pragma unroll
    for (int ks2 = 0; ks2 < 2; ++ks2) {
      bf16x8 pf = *(const bf16x8*)(pS + m16 * 72 + ks2 * 32 + quad * 8);
#pragma unroll
      for (int dt = 0; dt < 2; ++dt) {
        oacc[dt] = __builtin_amdgcn_mfma_f32_16x16x32_bf16(
            pf, vld[ks2 * 2 + dt], oacc[dt], 0, 0, 0);
      }
    }
  }

  // ---- epilogue: reduce row-sums within quad, normalize, store ----
#pragma unroll
  for (int off = 1; off < 16; off <<= 1)
#pragma unroll
    for (int i = 0; i < 4; ++i) rsp[i] += __shfl_xor(rsp[i], off, 64);
#pragma unroll
  for (int i = 0; i < 4; ++i) {
    float invs = 1.0f / rsp[i];
    int grow = row0 + wave * 16 + quad * 4 + i;
#pragma unroll
    for (int dt = 0; dt < 2; ++dt) {
      attL[((size_t)b * 1024 + grow) * 256 + h * 32 + dt * 16 + m16] =
          __float2bfloat16(oacc[dt][i] * invs);
    }
  }
}

// ---------------------------------------------------------------------------
// K4: attnout 1x1 conv as MFMA GEMM 256 x 1024 x 256 per batch. (R6 version)
// ---------------------------------------------------------------------------
__global__ __launch_bounds__(256) void attnout_mfma_kernel(
    const bf16* __restrict__ attL, const float* __restrict__ w, const float* __restrict__ bias,
    float* __restrict__ out)
{
  __shared__ __align__(16) short smem[13824];
  short* aS = smem;            // [64 co][72]
  short* bS = smem + 4608;     // [128 l][72]

  int tid = threadIdx.x, lane = tid & 63, wave = tid >> 6;
  int m16 = lane & 15, quad = lane >> 4;
  int l0 = blockIdx.x * 128;
  int cotile = blockIdx.y;
  int b = blockIdx.z;
  int cbase = cotile * 64;

  f32x4 acc[8];
#pragma unroll
  for (int t = 0; t < 8; ++t) acc[t] = (f32x4){0.f, 0.f, 0.f, 0.f};

  for (int ck = 0; ck < 4; ++ck) {
    __syncthreads();
#pragma unroll
    for (int r = 0; r < 4; ++r) {            // A: 64 co x 64 ci from f32, cvt
      int u = r * 256 + tid;                  // 1024 float4 units
      int c = u >> 4, s4 = u & 15;
      float4 v = *(const float4*)(w + (size_t)(cbase + c) * 256 + ck * 64 + s4 * 4);
      unsigned int p0 = (unsigned int)f2bfbits(v.x) | ((unsigned int)f2bfbits(v.y) << 16);
      unsigned int p1 = (unsigned int)f2bfbits(v.z) | ((unsigned int)f2bfbits(v.w) << 16);
      uint2 u2; u2.x = p0; u2.y = p1;
      *(uint2*)(aS + c * 72 + s4 * 4) = u2;
    }
#pragma unroll
    for (int r = 0; r < 4; ++r) {            // B: 128 l x 64 ci bf16
      int u = r * 256 + tid;                  // 1024 uint4 units
      int l = u >> 3, seg = u & 7;
      *(uint4*)(bS + l * 72 + seg * 8) =
          *(const uint4*)(attL + ((size_t)(b * 1024) + l0 + l) * 256 + ck * 64 + seg * 8);
    }
    __syncthreads();
#pragma unroll
    for (int ks = 0; ks < 2; ++ks) {
      bf16x8 af = *(const bf16x8*)(aS + (wave * 16 + m16) * 72 + ks * 32 + quad * 8);
#pragma unroll
      for (int t = 0; t < 8; ++t) {
        bf16x8 bf = *(const bf16x8*)(bS + (t * 16 + m16) * 72 + ks * 32 + quad * 8);
        acc[t] = __builtin_amdgcn_mfma_f32_16x16x32_bf16(af, bf, acc[t], 0, 0, 0);
      }
    }
  }

  int co = cbase + wave * 16 + quad * 4;
#pragma unroll
  for (int i = 0; i < 4; ++i) {
    float bv = bias[co + i];
    size_t obase = ((size_t)(b * 512) + 256 + co + i) * 1024 + l0;
#pragma unroll
    for (int t = 0; t < 8; ++t)
      out[obase + t * 16 + m16] = acc[t][i] + bv;
  }
}

// ---------------------------------------------------------------------------
extern "C" void kernel_launch(void* const* d_in, const int* in_sizes, int n_in,
                              void* d_out, int out_size, void* d_ws, size_t ws_size,
                              hipStream_t stream) {
  const float* x      = (const float*)d_in[0];
  const float* w_qkv  = (const float*)d_in[1];
  const float* b_qkv  = (const float*)d_in[2];
  const float* w_attn = (const float*)d_in[3];
  const float* b_attn = (const float*)d_in[4];
  const float* w_out  = (const float*)d_in[5];
  const float* b_out  = (const float*)d_in[6];
  const float* krw    = (const float*)d_in[7];
  const float* krh    = (const float*)d_in[8];
  float* out = (float*)d_out;

  bf16* ws    = (bf16*)d_ws;
  bf16* xT    = ws;                 // [0, 2,097,152)   dead after qkv
  bf16* attL  = ws;                 // alias of xT      (attn -> attnout)
  bf16* wo_bf = ws + 2097152;       // [2,097,152, 2,686,976)  dead after conv3
  bf16* qT    = ws + 2097152;       // [2,097,152, 4,194,304)  written after conv3
  bf16* kR    = ws + 4194304;       // [4,194,304, 6,291,456)
  bf16* vW    = ws + 6291456;       // [6,291,456, 8,388,608)  exact 16 MB fit

  prep_kernel<<<dim3(2084), 256, 0, stream>>>(x, w_out, xT, wo_bf);
  conv3_mfma_kernel<<<dim3(256), 256, 0, stream>>>(xT, wo_bf, b_out, out);
  qkv_mfma_kernel<<<dim3(8, 12, 8), 256, 0, stream>>>(xT, w_qkv, b_qkv, qT, kR, vW);
  attn_mfma_kernel<<<dim3(1024), 256, 0, stream>>>(qT, kR, vW, krw, krh, attL);
  attnout_mfma_kernel<<<dim3(8, 4, 8), 256, 0, stream>>>(attL, w_attn, b_attn, out);
}

// Round 10
// 177.192 us; speedup vs baseline: 1.1670x; 1.0250x over previous
//
#include <hip/hip_runtime.h>
#include <hip/hip_bf16.h>

// AttentionConv2d: B=8, C_IN=256, H=W=32 (HW=1024), DK=DV=256, NH=8, DKH=DVH=32,
// C_OUT=512, 3x3 conv pad=1. fp32 storage in/out; bf16 intermediates + MFMA.
//
// Workspace (bf16 elements, EXACTLY 16 MB = 8,388,608 bf16 — proven safe size):
//   xT    [8 b][1024 l][256 ci]  @ 0          (dead after qkv)  } aliased later by
//   attL  [8 b][1024 l][256 ch]  @ 0          (attn -> attnout) } each other
//   wo_bf chunk-blocked          @ 2,097,152  (589,824; dead after conv3)
//   qT    [64 head][1024][32]    @ 2,097,152  (written by qkv AFTER conv3 -> safe alias
//                                              within the fused kernel: conv3 only READS
//                                              wo_bf; qkv blocks write qT. DISTINCT ranges?
//                                              wo_bf ends at 2,686,976; qT starts 2,097,152
//                                              -> OVERLAP. So in the fused kernel qT must
//                                              NOT alias wo_bf. Moved qT to the attL space
//                                              instead (xT dead only after qkv...) -> keep
//                                              it simple: qT gets its own slot, see below.
//   kR    [64 head][1024][32]    @ 4,194,304
//   vW    [64 head][32][1024]    @ 6,291,456
// R10 layout (no aliasing hazards with fused conv3+qkv):
//   xT    @ 0          (2,097,152)   read by conv3+qkv (fused)
//   attL  @ 0          alias of xT   (attn writes AFTER fused kernel done -> safe)
//   qT    @ 2,097,152  (2,097,152)   } qkv writes; wo_bf moved to live INSIDE vW's
//   kR    @ 4,194,304  (2,097,152)   } slot? No: wo_bf (589,824) placed at tail of
//   vW    @ 6,291,456  (2,097,152)     qT? Also unsafe. Solution: wo_bf @ 7,798,784
//         -> overlaps vW tail. vW written by qkv WHILE conv3 reads wo_bf -> hazard!
// Final safe layout: shrink nothing — wo_bf gets the LAST 589,824 of attL/xT? xT is
// read concurrently. TRUE solution: ws is 16 MB min but may be larger; however we
// must assume exactly 16 MB. Place wo_bf in the qT slot tail: qT occupies
// [2,097,152, 4,194,304) but only needs 2,097,152... it needs all of it.
// => Give vW only [6,291,456, 7,798,784) ? vW needs 2,097,152. No spare room.
// => Repack: q/k/v are 3 x 2,097,152 = 6,291,456; xT/attL 2,097,152; total 8,388,608.
//    wo_bf must overlap something not live during fused kernel: attL! attL is written
//    by attn (after fused kernel completes) and read by attnout. wo_bf is read only
//    during the fused kernel. But attL aliases xT which IS live (read) during fused.
//    xT uses all 2,097,152 of that slot... xT is [8][1024][256] = 2,097,152 exactly.
// => Keep wo_bf where it was and DELAY qkv's qT writes? qT would collide with wo_bf
//    only in [2,097,152, 2,686,976) = heads 0..17 of qT. conv3 blocks read wo_bf
//    while qkv blocks write qT -> real hazard in the fused kernel.
// => Clean fix: store conv3 weights NOT in ws but recompute layout so wo_bf lives in
//    the UNUSED fp32 output region? d_out is 8*512*1024 fp32 = 16 MB, fully written.
//    channels 0..255 are written by conv3 itself at the END of each block (after all
//    wo_bf reads by THAT block, but other blocks may still read wo_bf) -> hazard.
// => Simplest safe option: keep kernels' LAUNCH split as before for wo_bf lifetime,
//    i.e. fuse qkv with conv3 but source conv3 weights from a wo_bf copy placed in
//    the kR slot tail? kR written by qkv concurrently. NO.
// => Give up intra-ws placement: put wo_bf at tail of vW and make qkv write vW heads
//    0..55 only... v needs all 64 heads.
// FINAL: prep writes wo_bf into [2,097,152, 2,686,976) as before, and the fused
// kernel's qkv part SKIPS writing qT for the colliding region by ... noone writes
// qT there except qkv. Hazard is conv3 READS wo_bf vs qkv WRITES qT same bytes.
// Resolve by ORDER within the fused kernel: conv3 blocks (0..255) load ALL their
// wo_bf data... over 8 chunks spread across the whole kernel. Not orderable.
// => Decision: qT moves to a REPACKED slot: store qT as [64][1024][32] in the
//    attL/xT region IS impossible; instead note kR+vW+qT need 6 MB and xT 2 MB:
//    8,388,608 total leaves 0 spare. wo_bf (589,824) forces overlap somewhere.
//    The ONLY region dead during the fused kernel is NONE. So: eliminate wo_bf —
//    fused kernel's conv3 part converts w_out fp32->bf16 on the fly during staging
//    (like qkv's A staging does): reads w_out fp32 directly with the chunk-blocked
//    gather done per-block. w_out fp32 reads: 36 KB/chunk/block *as fp32* = 72 KB,
//    gathered with stride-9 scalar reads -> that was why prep pre-packed it.
//    Compromise: prep still packs wo_bf, but into a NEW slot made by deferring xT:
//    conv3 does not need xT columns... it does.
// => PRAGMATIC RESOLUTION: keep 5 launches as-is (no hazard) but ALSO launch qkv
//    CONCURRENTLY by fusing qkv INTO conv3's launch is abandoned; instead fuse
//    qkv + attn? attn depends on qkv. Fuse prep+conv3? conv3 depends on prep.
//    The only independent pair needs wo_bf+qT alive simultaneously -> need 589,824
//    spare bf16 -> TAKE IT FROM pS! vW is [64][32][1024]; attn reads it. Fine:
//    shrink NOTHING and instead interleave qkv INTO the conv3 grid but have the
//    fused kernel write qT into the attL region [0..2,097,152) OFFSET? attL region
//    = xT which conv3/qkv READ. Writing qT there while others read xT = hazard.
// CONCLUSION: fusion requires wo_bf gone. On-the-fly fp32 w_out staging it is:
// conv3 part reads w_out fp32 (chunk-gather, coalesced within rows of 9) and
// converts during LDS store. Costs ~2x staging bytes for w (72KB/chunk/block from
// L2-cached w_out, 2.3 MB total fp32) — acceptable; prep drops its w_out half.

typedef __hip_bfloat16 bf16;
typedef __attribute__((ext_vector_type(8))) short bf16x8;
typedef __attribute__((ext_vector_type(4))) float f32x4;

__device__ __forceinline__ float bf2f(bf16 v) { return __bfloat162float(v); }
__device__ __forceinline__ float blo(unsigned int v) { return __uint_as_float(v << 16); }
__device__ __forceinline__ float bhi(unsigned int v) { return __uint_as_float(v & 0xffff0000u); }
__device__ __forceinline__ unsigned short f2bfbits(float f) {
  union { bf16 h; unsigned short u; } cv; cv.h = __float2bfloat16(f); return cv.u;
}
// cheap round-to-nearest (ties away): 2 VALU ops; <=1 ulp vs RNE.
__device__ __forceinline__ short f2bfr(float f) {
  return (short)((__float_as_uint(f) + 0x8000u) >> 16);
}

// ---------------------------------------------------------------------------
// K0: prep — xT transpose to bf16 only (w_out conversion now in-kernel). grid 2048.
// ---------------------------------------------------------------------------
__global__ __launch_bounds__(256) void prep_kernel(
    const float* __restrict__ x, bf16* __restrict__ xT)
{
  int bid = blockIdx.x, tid = threadIdx.x;
  __shared__ float t[32 * 33];
  int b = bid >> 8, rem = bid & 255;
  int ci0 = (rem >> 5) * 32, l0 = (rem & 31) * 32;
  {
    int ciL = tid >> 3, lL4 = (tid & 7) * 4;
    float4 v = *(const float4*)(x + (size_t)(b * 256 + ci0 + ciL) * 1024 + l0 + lL4);
    t[ciL * 33 + lL4 + 0] = v.x; t[ciL * 33 + lL4 + 1] = v.y;
    t[ciL * 33 + lL4 + 2] = v.z; t[ciL * 33 + lL4 + 3] = v.w;
  }
  __syncthreads();
  {
    int lL = tid >> 3, cS = (tid & 7) * 4;
    unsigned int p0 = (unsigned int)f2bfbits(t[(cS + 0) * 33 + lL]) |
                      ((unsigned int)f2bfbits(t[(cS + 1) * 33 + lL]) << 16);
    unsigned int p1 = (unsigned int)f2bfbits(t[(cS + 2) * 33 + lL]) |
                      ((unsigned int)f2bfbits(t[(cS + 3) * 33 + lL]) << 16);
    uint2 u2; u2.x = p0; u2.y = p1;
    *(uint2*)(xT + ((size_t)(b * 1024) + l0 + lL) * 256 + ci0 + cS) = u2;
  }
}

// ---------------------------------------------------------------------------
// K1 (fused): blocks 0..255 = conv3 (3x3, MFMA shift-GEMM); 256..1023 = qkv GEMM.
// Independent work (both only read xT) -> co-resident on CUs, mutual latency hiding.
// conv3 stages w_out straight from fp32 (gather of float2 pairs along ci).
// ---------------------------------------------------------------------------
__global__ __launch_bounds__(256) void convqkv_kernel(
    const bf16* __restrict__ xT,
    const float* __restrict__ wout, const float* __restrict__ b_out, float* __restrict__ out,
    const float* __restrict__ wq, const float* __restrict__ b_qkv,
    bf16* __restrict__ qT, bf16* __restrict__ kR, bf16* __restrict__ vW)
{
  __shared__ __align__(16) short smem[27104];
  int tid = threadIdx.x, lane = tid & 63, wave = tid >> 6;
  int m16 = lane & 15, quad = lane >> 4;

  if (blockIdx.x < 256) {
    // ================= conv3: 64 co x 128 spatial (4 rows) ==================
    short* wS = smem;            // [64 co][296] (288 = 9 kidx * 32 ci)
    short* xS = smem + 18944;    // [6 rows][34 cols][40]
    int bid = blockIdx.x;
    int rc = bid & 7, cotile = (bid >> 3) & 3, b = bid >> 5;
    int y0 = rc * 4;

    f32x4 acc[8];
#pragma unroll
    for (int t = 0; t < 8; ++t) acc[t] = (f32x4){0.f, 0.f, 0.f, 0.f};

    for (int ck = 0; ck < 8; ++ck) {
      __syncthreads();
      // w staging from fp32: 2304 units of 8 bf16; unit u -> co=u/36, r=u%36
      // (r = kidx*4+cig), src = wout[(co*256 + ck*32 + cig*8 + j)*9 + kidx]
#pragma unroll
      for (int r = 0; r < 9; ++r) {
        int u = r * 256 + tid;
        int co = u / 36, rr = u % 36;
        int kidx = rr >> 2, cig = rr & 3;
        const float* src = wout + (size_t)((cotile * 64 + co) * 256 + ck * 32 + cig * 8) * 9 + kidx;
        union { unsigned short h[8]; uint4 u4; } pk;
#pragma unroll
        for (int j = 0; j < 8; ++j) pk.h[j] = f2bfbits(src[j * 9]);
        *(uint4*)(wS + co * 296 + rr * 8) = pk.u4;
      }
#pragma unroll
      for (int r = 0; r < 3; ++r) {          // x: 768 units (6 rows x 32 cols x 4 segs)
        int u = r * 256 + tid;
        int pos = u >> 2, seg = u & 3;
        int row = pos >> 5, col = pos & 31;
        int gy = y0 - 1 + row;
        uint4 val = make_uint4(0u, 0u, 0u, 0u);
        if (gy >= 0 && gy < 32)
          val = *(const uint4*)(xT + ((size_t)(b * 1024) + gy * 32 + col) * 256 + ck * 32 + seg * 8);
        *(uint4*)(xS + (row * 34 + col + 1) * 40 + seg * 8) = val;
      }
      if (tid < 48) {                         // zero halo cols (x=-1, x=32)
        int pos = tid >> 2, seg = tid & 3;
        int row = pos >> 1, side = pos & 1;
        *(uint4*)(xS + (row * 34 + side * 33) * 40 + seg * 8) = make_uint4(0u, 0u, 0u, 0u);
      }
      __syncthreads();
#pragma unroll
      for (int kidx = 0; kidx < 9; ++kidx) {
        int dy = kidx / 3, dx = kidx - dy * 3;
        bf16x8 af = *(const bf16x8*)(wS + (wave * 16 + m16) * 296 + kidx * 32 + quad * 8);
#pragma unroll
        for (int t = 0; t < 8; ++t) {
          int row = (t >> 1) + dy;
          int col = (t & 1) * 16 + m16 + dx;
          bf16x8 bf = *(const bf16x8*)(xS + (row * 34 + col) * 40 + quad * 8);
          acc[t] = __builtin_amdgcn_mfma_f32_16x16x32_bf16(af, bf, acc[t], 0, 0, 0);
        }
      }
    }

    int cob = cotile * 64 + wave * 16 + quad * 4;
#pragma unroll
    for (int i = 0; i < 4; ++i) {
      float bv = b_out[cob + i];
#pragma unroll
      for (int t = 0; t < 8; ++t) {
        int y = y0 + (t >> 1), xc = (t & 1) * 16 + m16;
        out[((size_t)(b * 512) + cob + i) * 1024 + y * 32 + xc] = acc[t][i] + bv;
      }
    }
  } else {
    // ================= qkv: GEMM 768 x 1024 x 256 per batch =================
    short* aS = smem;            // [64][72]
    short* bS = smem + 4608;     // [128][72]
    int bid2 = blockIdx.x - 256;
    int ltile = bid2 & 7;
    int rest = bid2 >> 3;        // 0..95
    int ctile = rest % 12;
    int b = rest / 12;
    int l0 = ltile * 128;
    int cbase = ctile * 64;

    f32x4 acc[8];
#pragma unroll
    for (int t = 0; t < 8; ++t) acc[t] = (f32x4){0.f, 0.f, 0.f, 0.f};

    for (int ck = 0; ck < 4; ++ck) {
      __syncthreads();
#pragma unroll
      for (int r = 0; r < 4; ++r) {          // A: 64 c x 64 ci from f32, cvt
        int u = r * 256 + tid;
        int c = u >> 4, s4 = u & 15;
        float4 v = *(const float4*)(wq + (size_t)(cbase + c) * 256 + ck * 64 + s4 * 4);
        unsigned int p0 = (unsigned int)f2bfbits(v.x) | ((unsigned int)f2bfbits(v.y) << 16);
        unsigned int p1 = (unsigned int)f2bfbits(v.z) | ((unsigned int)f2bfbits(v.w) << 16);
        uint2 u2; u2.x = p0; u2.y = p1;
        *(uint2*)(aS + c * 72 + s4 * 4) = u2;
      }
#pragma unroll
      for (int r = 0; r < 4; ++r) {          // B: 128 l x 64 ci bf16
        int u = r * 256 + tid;
        int l = u >> 3, seg = u & 7;
        *(uint4*)(bS + l * 72 + seg * 8) =
            *(const uint4*)(xT + ((size_t)(b * 1024) + l0 + l) * 256 + ck * 64 + seg * 8);
      }
      __syncthreads();
#pragma unroll
      for (int ks = 0; ks < 2; ++ks) {
        bf16x8 af = *(const bf16x8*)(aS + (wave * 16 + m16) * 72 + ks * 32 + quad * 8);
#pragma unroll
        for (int t = 0; t < 8; ++t) {
          bf16x8 bf = *(const bf16x8*)(bS + (t * 16 + m16) * 72 + ks * 32 + quad * 8);
          acc[t] = __builtin_amdgcn_mfma_f32_16x16x32_bf16(af, bf, acc[t], 0, 0, 0);
        }
      }
    }

    __syncthreads();   // all waves done reading aS/bS; alias as transpose scratch
    short* ldsT = smem + wave * 3072;        // per-wave [128 l][24] (16 c used)
    int cb = cbase + wave * 16;
    bool isq = (ctile < 4);
    float bv[4];
#pragma unroll
    for (int i = 0; i < 4; ++i) bv[i] = b_qkv[cb + quad * 4 + i];
#pragma unroll
    for (int t = 0; t < 8; ++t) {
#pragma unroll
      for (int i = 0; i < 4; ++i) {
        float v = acc[t][i] + bv[i];
        if (isq) v *= 0.17677669529663689f;  // 32^-0.5, pre-rel-logits
        ldsT[(t * 16 + m16) * 24 + quad * 4 + i] = (short)f2bfbits(v);
      }
    }
    if (ctile < 8) {
      bf16* dst = isq ? qT : kR;
      int coff = isq ? cb : cb - 256;
#pragma unroll
      for (int rep = 0; rep < 4; ++rep) {
        int u = rep * 64 + lane;
        int l = u >> 1, half = u & 1;
        int c0 = coff + half * 8;
        int head = b * 8 + (c0 >> 5), d0 = c0 & 31;
        *(uint4*)(dst + ((size_t)head * 1024 + l0 + l) * 32 + d0) =
            *(const uint4*)(ldsT + l * 24 + half * 8);
      }
    } else {
      int dcol = lane >> 2, lg = lane & 3;
      int c2 = (cb - 512) + dcol;
      int head = b * 8 + (c2 >> 5), gd = c2 & 31;
#pragma unroll
      for (int s = 0; s < 4; ++s) {
        union { unsigned int w[4]; uint4 u4; } pk;
#pragma unroll
        for (int p = 0; p < 4; ++p) {
          int j0 = lg * 32 + s * 8 + p * 2;
          unsigned int u0 = (unsigned short)ldsT[j0 * 24 + dcol];
          unsigned int u1 = (unsigned short)ldsT[(j0 + 1) * 24 + dcol];
          pk.w[p] = u0 | (u1 << 16);
        }
        *(uint4*)(vW + ((size_t)head * 32 + gd) * 1024 + l0 + lg * 32 + s * 8) = pk.u4;
      }
    }
  }
}

// ---------------------------------------------------------------------------
// K3: MFMA attention, augmented-K rel logits (exact R6 version — best measured).
// ---------------------------------------------------------------------------
__global__ __launch_bounds__(256) void attn_mfma_kernel(
    const bf16* __restrict__ qT, const bf16* __restrict__ kR, const bf16* __restrict__ vW,
    const float* __restrict__ krw, const float* __restrict__ krh,
    bf16* __restrict__ attL)
{
  __shared__ __align__(16) char smem[31232];
  short* kaugS  = (short*)smem;              // [64 key][104]: k(32)|RWoh(32)|RHoh(32)
  short* vtS    = (short*)(smem + 13312);    // [32 d][72]
  short* atileS = (short*)(smem + 17920);    // prologue Atile / loop pS
  float* krwS   = (float*)smem;              // prologue alias
  float* krhS   = krwS + 63 * 33;

  int tid = threadIdx.x;
  int lane = tid & 63, wave = tid >> 6;
  int m16 = lane & 15, quad = lane >> 4;
  int bid = blockIdx.x;
  // same head -> same blockIdx mod 8 -> same XCD (round-robin heuristic)
  int head = ((bid & 7) << 3) | ((bid >> 3) & 7);
  int qt = bid >> 6;
  int row0 = qt * 64;
  int b = head >> 3, h = head & 7;

  // staging roles + chunk-0 prefetch (issue early; prologue hides latency)
  int skey = tid >> 2, sseg = tid & 3;       // K: 64 keys x 4 segs of 8
  int svd = tid >> 3, svk = tid & 7;         // V: 32 d x 8 key-segs of 8
  const bf16* kptr = kR + (size_t)head * 32768 + skey * 32 + sseg * 8;
  const bf16* vptr = vW + (size_t)head * 32768 + svd * 1024 + svk * 8;
  uint4 kreg = *(const uint4*)kptr;
  uint4 vreg = *(const uint4*)vptr;

  // ---- phase 0: stage krw/krh (padded x33) and q rows into Atile ----
  for (int i = tid; i < 504; i += 256) {
    int row = i >> 3, d0 = (i & 7) * 4;
    float4 a = *(const float4*)(krw + row * 32 + d0);
    krwS[row * 33 + d0 + 0] = a.x; krwS[row * 33 + d0 + 1] = a.y;
    krwS[row * 33 + d0 + 2] = a.z; krwS[row * 33 + d0 + 3] = a.w;
    float4 c = *(const float4*)(krh + row * 32 + d0);
    krhS[row * 33 + d0 + 0] = c.x; krhS[row * 33 + d0 + 1] = c.y;
    krhS[row * 33 + d0 + 2] = c.z; krhS[row * 33 + d0 + 3] = c.w;
  }
  {
    int r = tid >> 2, seg = tid & 3;
    uint4 u = *(const uint4*)(qT + ((size_t)head * 1024 + row0 + r) * 32 + seg * 8);
    *(uint4*)(atileS + r * 104 + seg * 8) = u;
  }
  __syncthreads();

  // ---- phase 1: RW/RH tables -> Atile[.][32..96) ----
  {
    int r = tid >> 2, jseg = tid & 3;
    int qi = r & 31;
    int qx = qt * 2 + (r >> 5);
    float q32[32];
#pragma unroll
    for (int s4 = 0; s4 < 4; ++s4) {
      uint4 u = ((const uint4*)(atileS + r * 104))[s4];
      q32[s4 * 8 + 0] = blo(u.x); q32[s4 * 8 + 1] = bhi(u.x);
      q32[s4 * 8 + 2] = blo(u.y); q32[s4 * 8 + 3] = bhi(u.y);
      q32[s4 * 8 + 4] = blo(u.z); q32[s4 * 8 + 5] = bhi(u.z);
      q32[s4 * 8 + 6] = blo(u.w); q32[s4 * 8 + 7] = bhi(u.w);
    }
    unsigned int pw[4], ph[4];
#pragma unroll
    for (int jp = 0; jp < 4; ++jp) {
      float sv[4] = {0.f, 0.f, 0.f, 0.f};
#pragma unroll 2
      for (int half = 0; half < 2; ++half) {
        int j = jseg * 8 + jp * 2 + half;
        const float* kw = krwS + (j - qi + 31) * 33;
        const float* kh = krhS + (j - qx + 31) * 33;
        float s1 = 0.f, s2 = 0.f;
#pragma unroll
        for (int d = 0; d < 32; ++d) { s1 += q32[d] * kw[d]; s2 += q32[d] * kh[d]; }
        sv[half] = s1; sv[2 + half] = s2;
      }
      pw[jp] = (unsigned int)(unsigned short)f2bfr(sv[0]) |
               ((unsigned int)(unsigned short)f2bfr(sv[1]) << 16);
      ph[jp] = (unsigned int)(unsigned short)f2bfr(sv[2]) |
               ((unsigned int)(unsigned short)f2bfr(sv[3]) << 16);
    }
#pragma unroll
    for (int jp = 0; jp < 4; ++jp) {
      ((unsigned int*)(atileS + r * 104 + 32 + jseg * 8))[jp] = pw[jp];
      ((unsigned int*)(atileS + r * 104 + 64 + jseg * 8))[jp] = ph[jp];
    }
  }
  __syncthreads();   // phase1 reads of krwS/krhS done; kaugS region now free

  // ---- one-hot init (once): zero [32,96), set RW one at 32+(key&31) ----
  {
    union { short s[16]; uint4 u4[2]; } oh;
#pragma unroll
    for (int e = 0; e < 16; ++e) oh.s[e] = 0;
    int base = 32 + sseg * 16;
    int pos = 32 + (skey & 31);
    if (pos >= base && pos < base + 16) oh.s[pos - base] = (short)0x3F80;
    ((uint4*)(kaugS + skey * 104 + 32 + sseg * 16))[0] = oh.u4[0];
    *((uint4*)(kaugS + skey * 104 + 32 + sseg * 16) + 1) = oh.u4[1];
  }

  // ---- persistent A-frags (q | RW | RH) ----
  bf16x8 afrag[3];
  {
    int arow = wave * 16 + m16;
#pragma unroll
    for (int ks = 0; ks < 3; ++ks)
      afrag[ks] = *(const bf16x8*)(atileS + arow * 104 + ks * 32 + quad * 8);
  }

  // ---- K-loop over 16 chunks of 64 keys, register-prefetched ----
  f32x4 oacc[2];
  oacc[0] = (f32x4){0.f, 0.f, 0.f, 0.f};
  oacc[1] = (f32x4){0.f, 0.f, 0.f, 0.f};
  float rsp[4] = {0.f, 0.f, 0.f, 0.f};
  short* pS = (short*)(smem + 17920) + wave * 1152;   // [16 q][72 key-padded]

  for (int c = 0; c < 16; ++c) {
    __syncthreads();                          // prev compute done reading LDS
    *(uint4*)(kaugS + skey * 104 + sseg * 8) = kreg;
    if (sseg == 0) {                          // RH one-hot shift (+2 per chunk)
      if (c) kaugS[skey * 104 + 64 + (c - 1) * 2 + (skey >> 5)] = 0;
      kaugS[skey * 104 + 64 + c * 2 + (skey >> 5)] = (short)0x3F80;
    }
    *(uint4*)(vtS + svd * 72 + svk * 8) = vreg;
    if (c < 15) {                             // prefetch next chunk (latency
      kreg = *(const uint4*)(kptr + (c + 1) * 2048);  //  overlaps compute below)
      vreg = *(const uint4*)(vptr + (c + 1) * 64);
    }
    __syncthreads();                          // staging visible

    // QK^T (augmented K-dim 96): 4 n-tiles x 3 k-steps
    f32x4 sacc[4];
#pragma unroll
    for (int t = 0; t < 4; ++t) sacc[t] = (f32x4){0.f, 0.f, 0.f, 0.f};
#pragma unroll
    for (int t = 0; t < 4; ++t) {
#pragma unroll
      for (int ks = 0; ks < 3; ++ks) {
        bf16x8 bfK = *(const bf16x8*)(kaugS + (t * 16 + m16) * 104 + ks * 32 + quad * 8);
        sacc[t] = __builtin_amdgcn_mfma_f32_16x16x32_bf16(afrag[ks], bfK, sacc[t], 0, 0, 0);
      }
    }
    // exp (no max-sub: logits bounded), row-sum partials, P -> LDS (C/D->A)
#pragma unroll
    for (int t = 0; t < 4; ++t) {
#pragma unroll
      for (int i = 0; i < 4; ++i) {
        float e = __expf(sacc[t][i]);
        rsp[i] += e;
        pS[(quad * 4 + i) * 72 + t * 16 + m16] = f2bfr(e);
      }
    }
    // PV: 2 k-steps (32 keys) x 2 d-tiles
#pragma unroll
    for (int ks2 = 0; ks2 < 2; ++ks2) {
      bf16x8 pf = *(const bf16x8*)(pS + m16 * 72 + ks2 * 32 + quad * 8);
#pragma unroll
      for (int dt = 0; dt < 2; ++dt) {
        bf16x8 vf = *(const bf16x8*)(vtS + (dt * 16 + m16) * 72 + ks2 * 32 + quad * 8);
        oacc[dt] = __builtin_amdgcn_mfma_f32_16x16x32_bf16(pf, vf, oacc[dt], 0, 0, 0);
      }
    }
  }

  // ---- epilogue: reduce row-sums within quad, normalize, store ----
#pragma unroll
  for (int off = 1; off < 16; off <<= 1)
#pragma unroll
    for (int i = 0; i < 4; ++i) rsp[i] += __shfl_xor(rsp[i], off, 64);
#pragma unroll
  for (int i = 0; i < 4; ++i) {
    float invs = 1.0f / rsp[i];
    int grow = row0 + wave * 16 + quad * 4 + i;
#pragma unroll
    for (int dt = 0; dt < 2; ++dt) {
      attL[((size_t)b * 1024 + grow) * 256 + h * 32 + dt * 16 + m16] =
          __float2bfloat16(oacc[dt][i] * invs);
    }
  }
}

// ---------------------------------------------------------------------------
// K4: attnout 1x1 conv as MFMA GEMM 256 x 1024 x 256 per batch. (R6 version)
// ---------------------------------------------------------------------------
__global__ __launch_bounds__(256) void attnout_mfma_kernel(
    const bf16* __restrict__ attL, const float* __restrict__ w, const float* __restrict__ bias,
    float* __restrict__ out)
{
  __shared__ __align__(16) short smem[13824];
  short* aS = smem;            // [64 co][72]
  short* bS = smem + 4608;     // [128 l][72]

  int tid = threadIdx.x, lane = tid & 63, wave = tid >> 6;
  int m16 = lane & 15, quad = lane >> 4;
  int l0 = blockIdx.x * 128;
  int cotile = blockIdx.y;
  int b = blockIdx.z;
  int cbase = cotile * 64;

  f32x4 acc[8];
#pragma unroll
  for (int t = 0; t < 8; ++t) acc[t] = (f32x4){0.f, 0.f, 0.f, 0.f};

  for (int ck = 0; ck < 4; ++ck) {
    __syncthreads();
#pragma unroll
    for (int r = 0; r < 4; ++r) {            // A: 64 co x 64 ci from f32, cvt
      int u = r * 256 + tid;
      int c = u >> 4, s4 = u & 15;
      float4 v = *(const float4*)(w + (size_t)(cbase + c) * 256 + ck * 64 + s4 * 4);
      unsigned int p0 = (unsigned int)f2bfbits(v.x) | ((unsigned int)f2bfbits(v.y) << 16);
      unsigned int p1 = (unsigned int)f2bfbits(v.z) | ((unsigned int)f2bfbits(v.w) << 16);
      uint2 u2; u2.x = p0; u2.y = p1;
      *(uint2*)(aS + c * 72 + s4 * 4) = u2;
    }
#pragma unroll
    for (int r = 0; r < 4; ++r) {            // B: 128 l x 64 ci bf16
      int u = r * 256 + tid;
      int l = u >> 3, seg = u & 7;
      *(uint4*)(bS + l * 72 + seg * 8) =
          *(const uint4*)(attL + ((size_t)(b * 1024) + l0 + l) * 256 + ck * 64 + seg * 8);
    }
    __syncthreads();
#pragma unroll
    for (int ks = 0; ks < 2; ++ks) {
      bf16x8 af = *(const bf16x8*)(aS + (wave * 16 + m16) * 72 + ks * 32 + quad * 8);
#pragma unroll
      for (int t = 0; t < 8; ++t) {
        bf16x8 bf = *(const bf16x8*)(bS + (t * 16 + m16) * 72 + ks * 32 + quad * 8);
        acc[t] = __builtin_amdgcn_mfma_f32_16x16x32_bf16(af, bf, acc[t], 0, 0, 0);
      }
    }
  }

  int co = cbase + wave * 16 + quad * 4;
#pragma unroll
  for (int i = 0; i < 4; ++i) {
    float bv = bias[co + i];
    size_t obase = ((size_t)(b * 512) + 256 + co + i) * 1024 + l0;
#pragma unroll
    for (int t = 0; t < 8; ++t)
      out[obase + t * 16 + m16] = acc[t][i] + bv;
  }
}

// ---------------------------------------------------------------------------
extern "C" void kernel_launch(void* const* d_in, const int* in_sizes, int n_in,
                              void* d_out, int out_size, void* d_ws, size_t ws_size,
                              hipStream_t stream) {
  const float* x      = (const float*)d_in[0];
  const float* w_qkv  = (const float*)d_in[1];
  const float* b_qkv  = (const float*)d_in[2];
  const float* w_attn = (const float*)d_in[3];
  const float* b_attn = (const float*)d_in[4];
  const float* w_out  = (const float*)d_in[5];
  const float* b_out  = (const float*)d_in[6];
  const float* krw    = (const float*)d_in[7];
  const float* krh    = (const float*)d_in[8];
  float* out = (float*)d_out;

  bf16* ws    = (bf16*)d_ws;
  bf16* xT    = ws;                 // [0, 2,097,152)  read by fused conv3+qkv
  bf16* attL  = ws;                 // alias of xT     (attn -> attnout, after fused)
  bf16* qT    = ws + 2097152;       // [2,097,152, 4,194,304)
  bf16* kR    = ws + 4194304;       // [4,194,304, 6,291,456)
  bf16* vW    = ws + 6291456;       // [6,291,456, 8,388,608)  exact 16 MB fit

  prep_kernel<<<dim3(2048), 256, 0, stream>>>(x, xT);
  convqkv_kernel<<<dim3(1024), 256, 0, stream>>>(xT, w_out, b_out, out,
                                                 w_qkv, b_qkv, qT, kR, vW);
  attn_mfma_kernel<<<dim3(1024), 256, 0, stream>>>(qT, kR, vW, krw, krh, attL);
  attnout_mfma_kernel<<<dim3(8, 4, 8), 256, 0, stream>>>(attL, w_attn, b_attn, out);
}

// Round 11
// 163.181 us; speedup vs baseline: 1.2672x; 1.0859x over previous
//
#include <hip/hip_runtime.h>
#include <hip/hip_bf16.h>

// AttentionConv2d: B=8, C_IN=256, H=W=32 (HW=1024), DK=DV=256, NH=8, DKH=DVH=32,
// C_OUT=512, 3x3 conv pad=1. fp32 storage in/out; bf16 intermediates + MFMA.
//
// Workspace (bf16 elements, EXACTLY 16 MB):
//   xT    [8 b][1024 l][256 ci]  @ 0          read by fused conv3+qkv
//   attL  [8 b][1024 l][256 ch]  @ 0          alias of xT (attn writes after fused done)
//   qT    [64 head][1024][32]    @ 2,097,152
//   kR    [64 head][1024][32]    @ 4,194,304
//   vW    [64 head][32][1024]    @ 6,291,456
// wo_bf (prepacked bf16 conv3 weights, 589,824 elems) lives in D_OUT's attention
// half (channels 256+), which is dead from launch until attnout overwrites it:
//   wob0 = 28 chunkblks in out[b0][ch256+] region; wob1 = 4 chunkblks in out[b1][ch256+].
// Lifetime: prep writes wo_bf -> convqkv reads it (conv3 writes only ch0..255,
// disjoint) -> attn -> attnout overwrites ch256+. Stream-serial => safe.
// Kernel order: prep -> convqkv(fused) -> attn -> attnout.

typedef __hip_bfloat16 bf16;
typedef __attribute__((ext_vector_type(8))) short bf16x8;
typedef __attribute__((ext_vector_type(4))) float f32x4;

__device__ __forceinline__ float bf2f(bf16 v) { return __bfloat162float(v); }
__device__ __forceinline__ float blo(unsigned int v) { return __uint_as_float(v << 16); }
__device__ __forceinline__ float bhi(unsigned int v) { return __uint_as_float(v & 0xffff0000u); }
__device__ __forceinline__ unsigned short f2bfbits(float f) {
  union { bf16 h; unsigned short u; } cv; cv.h = __float2bfloat16(f); return cv.u;
}
// cheap round-to-nearest (ties away): 2 VALU ops; <=1 ulp vs RNE.
__device__ __forceinline__ short f2bfr(float f) {
  return (short)((__float_as_uint(f) + 0x8000u) >> 16);
}

// ---------------------------------------------------------------------------
// K0: prep — xT transpose to bf16 + w_out bf16 chunk-blocked into wob0/wob1.
// blocks 0..2047: xT; 2048..2083: w_out. grid 2084.
// wo_bf layout: chunkblk = (co>>6)*8 + (ci>>5); within: [co&63][kidx 9][(ci&31)/8]
// (18432 bf16/chunkblk; chunkblk cb<28 -> wob0+cb*18432, else wob1+(cb-28)*18432)
// ---------------------------------------------------------------------------
__global__ __launch_bounds__(256) void prep_kernel(
    const float* __restrict__ x, const float* __restrict__ wout,
    bf16* __restrict__ xT, bf16* __restrict__ wob0, bf16* __restrict__ wob1)
{
  int bid = blockIdx.x, tid = threadIdx.x;
  if (bid < 2048) {
    __shared__ float t[32 * 33];
    int b = bid >> 8, rem = bid & 255;
    int ci0 = (rem >> 5) * 32, l0 = (rem & 31) * 32;
    {
      int ciL = tid >> 3, lL4 = (tid & 7) * 4;
      float4 v = *(const float4*)(x + (size_t)(b * 256 + ci0 + ciL) * 1024 + l0 + lL4);
      t[ciL * 33 + lL4 + 0] = v.x; t[ciL * 33 + lL4 + 1] = v.y;
      t[ciL * 33 + lL4 + 2] = v.z; t[ciL * 33 + lL4 + 3] = v.w;
    }
    __syncthreads();
    {
      int lL = tid >> 3, cS = (tid & 7) * 4;
      unsigned int p0 = (unsigned int)f2bfbits(t[(cS + 0) * 33 + lL]) |
                        ((unsigned int)f2bfbits(t[(cS + 1) * 33 + lL]) << 16);
      unsigned int p1 = (unsigned int)f2bfbits(t[(cS + 2) * 33 + lL]) |
                        ((unsigned int)f2bfbits(t[(cS + 3) * 33 + lL]) << 16);
      uint2 u2; u2.x = p0; u2.y = p1;
      *(uint2*)(xT + ((size_t)(b * 1024) + l0 + lL) * 256 + ci0 + cS) = u2;
    }
  } else {
    int t0 = (bid - 2048) * 256 + tid;       // 0..9215
#pragma unroll
    for (int s = 0; s < 8; ++s) {
      int u = s * 9216 + t0;                 // dst uint4 index 0..73727
      int chunkblk = u / 2304;
      int within = u - chunkblk * 2304;
      int co63 = within / 36;
      int r = within - co63 * 36;            // kidx*4 + cig
      int kidx = r >> 2, cig = r & 3;
      int co = (chunkblk >> 3) * 64 + co63;
      int ci = (chunkblk & 7) * 32 + cig * 8;
      union { unsigned short h[8]; uint4 u4; } pk;
#pragma unroll
      for (int j = 0; j < 8; ++j)
        pk.h[j] = f2bfbits(wout[(size_t)(co * 256 + ci + j) * 9 + kidx]);
      bf16* dst = (chunkblk < 28) ? (wob0 + (size_t)chunkblk * 18432)
                                  : (wob1 + (size_t)(chunkblk - 28) * 18432);
      *(uint4*)(dst + (size_t)within * 8) = pk.u4;
    }
  }
}

// ---------------------------------------------------------------------------
// K1 (fused): blocks 0..255 = conv3 (3x3, MFMA shift-GEMM, prepacked weights);
// 256..1023 = qkv GEMM. Both only read xT -> co-resident, mutual latency hiding.
// ---------------------------------------------------------------------------
__global__ __launch_bounds__(256) void convqkv_kernel(
    const bf16* __restrict__ xT,
    const bf16* __restrict__ wob0, const bf16* __restrict__ wob1,
    const float* __restrict__ b_out, float* __restrict__ out,
    const float* __restrict__ wq, const float* __restrict__ b_qkv,
    bf16* __restrict__ qT, bf16* __restrict__ kR, bf16* __restrict__ vW)
{
  __shared__ __align__(16) short smem[27104];
  int tid = threadIdx.x, lane = tid & 63, wave = tid >> 6;
  int m16 = lane & 15, quad = lane >> 4;

  if (blockIdx.x < 256) {
    // ================= conv3: 64 co x 128 spatial (4 rows) ==================
    short* wS = smem;            // [64 co][296] (288 = 9 kidx * 32 ci)
    short* xS = smem + 18944;    // [6 rows][34 cols][40]
    int bid = blockIdx.x;
    int rc = bid & 7, cotile = (bid >> 3) & 3, b = bid >> 5;
    int y0 = rc * 4;

    f32x4 acc[8];
#pragma unroll
    for (int t = 0; t < 8; ++t) acc[t] = (f32x4){0.f, 0.f, 0.f, 0.f};

    for (int ck = 0; ck < 8; ++ck) {
      __syncthreads();
      int cb = cotile * 8 + ck;
      const bf16* wbase = (cb < 28) ? (wob0 + (size_t)cb * 18432)
                                    : (wob1 + (size_t)(cb - 28) * 18432);
#pragma unroll
      for (int r = 0; r < 9; ++r) {          // 2304 uint4 units
        int u = r * 256 + tid;
        *(uint4*)(wS + (u / 36) * 296 + (u % 36) * 8) = *(const uint4*)(wbase + (size_t)u * 8);
      }
#pragma unroll
      for (int r = 0; r < 3; ++r) {          // x: 768 units (6 rows x 32 cols x 4 segs)
        int u = r * 256 + tid;
        int pos = u >> 2, seg = u & 3;
        int row = pos >> 5, col = pos & 31;
        int gy = y0 - 1 + row;
        uint4 val = make_uint4(0u, 0u, 0u, 0u);
        if (gy >= 0 && gy < 32)
          val = *(const uint4*)(xT + ((size_t)(b * 1024) + gy * 32 + col) * 256 + ck * 32 + seg * 8);
        *(uint4*)(xS + (row * 34 + col + 1) * 40 + seg * 8) = val;
      }
      if (tid < 48) {                         // zero halo cols (x=-1, x=32)
        int pos = tid >> 2, seg = tid & 3;
        int row = pos >> 1, side = pos & 1;
        *(uint4*)(xS + (row * 34 + side * 33) * 40 + seg * 8) = make_uint4(0u, 0u, 0u, 0u);
      }
      __syncthreads();
#pragma unroll
      for (int kidx = 0; kidx < 9; ++kidx) {
        int dy = kidx / 3, dx = kidx - dy * 3;
        bf16x8 af = *(const bf16x8*)(wS + (wave * 16 + m16) * 296 + kidx * 32 + quad * 8);
#pragma unroll
        for (int t = 0; t < 8; ++t) {
          int row = (t >> 1) + dy;
          int col = (t & 1) * 16 + m16 + dx;
          bf16x8 bf = *(const bf16x8*)(xS + (row * 34 + col) * 40 + quad * 8);
          acc[t] = __builtin_amdgcn_mfma_f32_16x16x32_bf16(af, bf, acc[t], 0, 0, 0);
        }
      }
    }

    int cob = cotile * 64 + wave * 16 + quad * 4;
#pragma unroll
    for (int i = 0; i < 4; ++i) {
      float bv = b_out[cob + i];
#pragma unroll
      for (int t = 0; t < 8; ++t) {
        int y = y0 + (t >> 1), xc = (t & 1) * 16 + m16;
        out[((size_t)(b * 512) + cob + i) * 1024 + y * 32 + xc] = acc[t][i] + bv;
      }
    }
  } else {
    // ================= qkv: GEMM 768 x 1024 x 256 per batch =================
    short* aS = smem;            // [64][72]
    short* bS = smem + 4608;     // [128][72]
    int bid2 = blockIdx.x - 256;
    int ltile = bid2 & 7;
    int rest = bid2 >> 3;        // 0..95
    int ctile = rest % 12;
    int b = rest / 12;
    int l0 = ltile * 128;
    int cbase = ctile * 64;

    f32x4 acc[8];
#pragma unroll
    for (int t = 0; t < 8; ++t) acc[t] = (f32x4){0.f, 0.f, 0.f, 0.f};

    for (int ck = 0; ck < 4; ++ck) {
      __syncthreads();
#pragma unroll
      for (int r = 0; r < 4; ++r) {          // A: 64 c x 64 ci from f32, cvt
        int u = r * 256 + tid;
        int c = u >> 4, s4 = u & 15;
        float4 v = *(const float4*)(wq + (size_t)(cbase + c) * 256 + ck * 64 + s4 * 4);
        unsigned int p0 = (unsigned int)f2bfbits(v.x) | ((unsigned int)f2bfbits(v.y) << 16);
        unsigned int p1 = (unsigned int)f2bfbits(v.z) | ((unsigned int)f2bfbits(v.w) << 16);
        uint2 u2; u2.x = p0; u2.y = p1;
        *(uint2*)(aS + c * 72 + s4 * 4) = u2;
      }
#pragma unroll
      for (int r = 0; r < 4; ++r) {          // B: 128 l x 64 ci bf16
        int u = r * 256 + tid;
        int l = u >> 3, seg = u & 7;
        *(uint4*)(bS + l * 72 + seg * 8) =
            *(const uint4*)(xT + ((size_t)(b * 1024) + l0 + l) * 256 + ck * 64 + seg * 8);
      }
      __syncthreads();
#pragma unroll
      for (int ks = 0; ks < 2; ++ks) {
        bf16x8 af = *(const bf16x8*)(aS + (wave * 16 + m16) * 72 + ks * 32 + quad * 8);
#pragma unroll
        for (int t = 0; t < 8; ++t) {
          bf16x8 bf = *(const bf16x8*)(bS + (t * 16 + m16) * 72 + ks * 32 + quad * 8);
          acc[t] = __builtin_amdgcn_mfma_f32_16x16x32_bf16(af, bf, acc[t], 0, 0, 0);
        }
      }
    }

    __syncthreads();   // all waves done reading aS/bS; alias as transpose scratch
    short* ldsT = smem + wave * 3072;        // per-wave [128 l][24] (16 c used)
    int cb = cbase + wave * 16;
    bool isq = (ctile < 4);
    float bv[4];
#pragma unroll
    for (int i = 0; i < 4; ++i) bv[i] = b_qkv[cb + quad * 4 + i];
#pragma unroll
    for (int t = 0; t < 8; ++t) {
#pragma unroll
      for (int i = 0; i < 4; ++i) {
        float v = acc[t][i] + bv[i];
        if (isq) v *= 0.17677669529663689f;  // 32^-0.5, pre-rel-logits
        ldsT[(t * 16 + m16) * 24 + quad * 4 + i] = (short)f2bfbits(v);
      }
    }
    if (ctile < 8) {
      bf16* dst = isq ? qT : kR;
      int coff = isq ? cb : cb - 256;
#pragma unroll
      for (int rep = 0; rep < 4; ++rep) {
        int u = rep * 64 + lane;
        int l = u >> 1, half = u & 1;
        int c0 = coff + half * 8;
        int head = b * 8 + (c0 >> 5), d0 = c0 & 31;
        *(uint4*)(dst + ((size_t)head * 1024 + l0 + l) * 32 + d0) =
            *(const uint4*)(ldsT + l * 24 + half * 8);
      }
    } else {
      int dcol = lane >> 2, lg = lane & 3;
      int c2 = (cb - 512) + dcol;
      int head = b * 8 + (c2 >> 5), gd = c2 & 31;
#pragma unroll
      for (int s = 0; s < 4; ++s) {
        union { unsigned int w[4]; uint4 u4; } pk;
#pragma unroll
        for (int p = 0; p < 4; ++p) {
          int j0 = lg * 32 + s * 8 + p * 2;
          unsigned int u0 = (unsigned short)ldsT[j0 * 24 + dcol];
          unsigned int u1 = (unsigned short)ldsT[(j0 + 1) * 24 + dcol];
          pk.w[p] = u0 | (u1 << 16);
        }
        *(uint4*)(vW + ((size_t)head * 32 + gd) * 1024 + l0 + lg * 32 + s * 8) = pk.u4;
      }
    }
  }
}

// ---------------------------------------------------------------------------
// K3: MFMA attention, augmented-K rel logits (R6 version — best measured).
// ---------------------------------------------------------------------------
__global__ __launch_bounds__(256) void attn_mfma_kernel(
    const bf16* __restrict__ qT, const bf16* __restrict__ kR, const bf16* __restrict__ vW,
    const float* __restrict__ krw, const float* __restrict__ krh,
    bf16* __restrict__ attL)
{
  __shared__ __align__(16) char smem[31232];
  short* kaugS  = (short*)smem;              // [64 key][104]: k(32)|RWoh(32)|RHoh(32)
  short* vtS    = (short*)(smem + 13312);    // [32 d][72]
  short* atileS = (short*)(smem + 17920);    // prologue Atile / loop pS
  float* krwS   = (float*)smem;              // prologue alias
  float* krhS   = krwS + 63 * 33;

  int tid = threadIdx.x;
  int lane = tid & 63, wave = tid >> 6;
  int m16 = lane & 15, quad = lane >> 4;
  int bid = blockIdx.x;
  // same head -> same blockIdx mod 8 -> same XCD (round-robin heuristic)
  int head = ((bid & 7) << 3) | ((bid >> 3) & 7);
  int qt = bid >> 6;
  int row0 = qt * 64;
  int b = head >> 3, h = head & 7;

  // staging roles + chunk-0 prefetch (issue early; prologue hides latency)
  int skey = tid >> 2, sseg = tid & 3;       // K: 64 keys x 4 segs of 8
  int svd = tid >> 3, svk = tid & 7;         // V: 32 d x 8 key-segs of 8
  const bf16* kptr = kR + (size_t)head * 32768 + skey * 32 + sseg * 8;
  const bf16* vptr = vW + (size_t)head * 32768 + svd * 1024 + svk * 8;
  uint4 kreg = *(const uint4*)kptr;
  uint4 vreg = *(const uint4*)vptr;

  // ---- phase 0: stage krw/krh (padded x33) and q rows into Atile ----
  for (int i = tid; i < 504; i += 256) {
    int row = i >> 3, d0 = (i & 7) * 4;
    float4 a = *(const float4*)(krw + row * 32 + d0);
    krwS[row * 33 + d0 + 0] = a.x; krwS[row * 33 + d0 + 1] = a.y;
    krwS[row * 33 + d0 + 2] = a.z; krwS[row * 33 + d0 + 3] = a.w;
    float4 c = *(const float4*)(krh + row * 32 + d0);
    krhS[row * 33 + d0 + 0] = c.x; krhS[row * 33 + d0 + 1] = c.y;
    krhS[row * 33 + d0 + 2] = c.z; krhS[row * 33 + d0 + 3] = c.w;
  }
  {
    int r = tid >> 2, seg = tid & 3;
    uint4 u = *(const uint4*)(qT + ((size_t)head * 1024 + row0 + r) * 32 + seg * 8);
    *(uint4*)(atileS + r * 104 + seg * 8) = u;
  }
  __syncthreads();

  // ---- phase 1: RW/RH tables -> Atile[.][32..96) ----
  {
    int r = tid >> 2, jseg = tid & 3;
    int qi = r & 31;
    int qx = qt * 2 + (r >> 5);
    float q32[32];
#pragma unroll
    for (int s4 = 0; s4 < 4; ++s4) {
      uint4 u = ((const uint4*)(atileS + r * 104))[s4];
      q32[s4 * 8 + 0] = blo(u.x); q32[s4 * 8 + 1] = bhi(u.x);
      q32[s4 * 8 + 2] = blo(u.y); q32[s4 * 8 + 3] = bhi(u.y);
      q32[s4 * 8 + 4] = blo(u.z); q32[s4 * 8 + 5] = bhi(u.z);
      q32[s4 * 8 + 6] = blo(u.w); q32[s4 * 8 + 7] = bhi(u.w);
    }
    unsigned int pw[4], ph[4];
#pragma unroll
    for (int jp = 0; jp < 4; ++jp) {
      float sv[4] = {0.f, 0.f, 0.f, 0.f};
#pragma unroll 2
      for (int half = 0; half < 2; ++half) {
        int j = jseg * 8 + jp * 2 + half;
        const float* kw = krwS + (j - qi + 31) * 33;
        const float* kh = krhS + (j - qx + 31) * 33;
        float s1 = 0.f, s2 = 0.f;
#pragma unroll
        for (int d = 0; d < 32; ++d) { s1 += q32[d] * kw[d]; s2 += q32[d] * kh[d]; }
        sv[half] = s1; sv[2 + half] = s2;
      }
      pw[jp] = (unsigned int)(unsigned short)f2bfr(sv[0]) |
               ((unsigned int)(unsigned short)f2bfr(sv[1]) << 16);
      ph[jp] = (unsigned int)(unsigned short)f2bfr(sv[2]) |
               ((unsigned int)(unsigned short)f2bfr(sv[3]) << 16);
    }
#pragma unroll
    for (int jp = 0; jp < 4; ++jp) {
      ((unsigned int*)(atileS + r * 104 + 32 + jseg * 8))[jp] = pw[jp];
      ((unsigned int*)(atileS + r * 104 + 64 + jseg * 8))[jp] = ph[jp];
    }
  }
  __syncthreads();   // phase1 reads of krwS/krhS done; kaugS region now free

  // ---- one-hot init (once): zero [32,96), set RW one at 32+(key&31) ----
  {
    union { short s[16]; uint4 u4[2]; } oh;
#pragma unroll
    for (int e = 0; e < 16; ++e) oh.s[e] = 0;
    int base = 32 + sseg * 16;
    int pos = 32 + (skey & 31);
    if (pos >= base && pos < base + 16) oh.s[pos - base] = (short)0x3F80;
    ((uint4*)(kaugS + skey * 104 + 32 + sseg * 16))[0] = oh.u4[0];
    *((uint4*)(kaugS + skey * 104 + 32 + sseg * 16) + 1) = oh.u4[1];
  }

  // ---- persistent A-frags (q | RW | RH) ----
  bf16x8 afrag[3];
  {
    int arow = wave * 16 + m16;
#pragma unroll
    for (int ks = 0; ks < 3; ++ks)
      afrag[ks] = *(const bf16x8*)(atileS + arow * 104 + ks * 32 + quad * 8);
  }

  // ---- K-loop over 16 chunks of 64 keys, register-prefetched ----
  f32x4 oacc[2];
  oacc[0] = (f32x4){0.f, 0.f, 0.f, 0.f};
  oacc[1] = (f32x4){0.f, 0.f, 0.f, 0.f};
  float rsp[4] = {0.f, 0.f, 0.f, 0.f};
  short* pS = (short*)(smem + 17920) + wave * 1152;   // [16 q][72 key-padded]

  for (int c = 0; c < 16; ++c) {
    __syncthreads();                          // prev compute done reading LDS
    *(uint4*)(kaugS + skey * 104 + sseg * 8) = kreg;
    if (sseg == 0) {                          // RH one-hot shift (+2 per chunk)
      if (c) kaugS[skey * 104 + 64 + (c - 1) * 2 + (skey >> 5)] = 0;
      kaugS[skey * 104 + 64 + c * 2 + (skey >> 5)] = (short)0x3F80;
    }
    *(uint4*)(vtS + svd * 72 + svk * 8) = vreg;
    if (c < 15) {                             // prefetch next chunk (latency
      kreg = *(const uint4*)(kptr + (c + 1) * 2048);  //  overlaps compute below)
      vreg = *(const uint4*)(vptr + (c + 1) * 64);
    }
    __syncthreads();                          // staging visible

    // QK^T (augmented K-dim 96): 4 n-tiles x 3 k-steps
    f32x4 sacc[4];
#pragma unroll
    for (int t = 0; t < 4; ++t) sacc[t] = (f32x4){0.f, 0.f, 0.f, 0.f};
#pragma unroll
    for (int t = 0; t < 4; ++t) {
#pragma unroll
      for (int ks = 0; ks < 3; ++ks) {
        bf16x8 bfK = *(const bf16x8*)(kaugS + (t * 16 + m16) * 104 + ks * 32 + quad * 8);
        sacc[t] = __builtin_amdgcn_mfma_f32_16x16x32_bf16(afrag[ks], bfK, sacc[t], 0, 0, 0);
      }
    }
    // exp (no max-sub: logits bounded), row-sum partials, P -> LDS (C/D->A)
#pragma unroll
    for (int t = 0; t < 4; ++t) {
#pragma unroll
      for (int i = 0; i < 4; ++i) {
        float e = __expf(sacc[t][i]);
        rsp[i] += e;
        pS[(quad * 4 + i) * 72 + t * 16 + m16] = f2bfr(e);
      }
    }
    // PV: 2 k-steps (32 keys) x 2 d-tiles
#pragma unroll
    for (int ks2 = 0; ks2 < 2; ++ks2) {
      bf16x8 pf = *(const bf16x8*)(pS + m16 * 72 + ks2 * 32 + quad * 8);
#pragma unroll
      for (int dt = 0; dt < 2; ++dt) {
        bf16x8 vf = *(const bf16x8*)(vtS + (dt * 16 + m16) * 72 + ks2 * 32 + quad * 8);
        oacc[dt] = __builtin_amdgcn_mfma_f32_16x16x32_bf16(pf, vf, oacc[dt], 0, 0, 0);
      }
    }
  }

  // ---- epilogue: reduce row-sums within quad, normalize, store ----
#pragma unroll
  for (int off = 1; off < 16; off <<= 1)
#pragma unroll
    for (int i = 0; i < 4; ++i) rsp[i] += __shfl_xor(rsp[i], off, 64);
#pragma unroll
  for (int i = 0; i < 4; ++i) {
    float invs = 1.0f / rsp[i];
    int grow = row0 + wave * 16 + quad * 4 + i;
#pragma unroll
    for (int dt = 0; dt < 2; ++dt) {
      attL[((size_t)b * 1024 + grow) * 256 + h * 32 + dt * 16 + m16] =
          __float2bfloat16(oacc[dt][i] * invs);
    }
  }
}

// ---------------------------------------------------------------------------
// K4: attnout 1x1 conv as MFMA GEMM 256 x 1024 x 256 per batch. (R6 version)
// Runs last; overwrites the d_out ch256+ regions that hosted wo_bf.
// ---------------------------------------------------------------------------
__global__ __launch_bounds__(256) void attnout_mfma_kernel(
    const bf16* __restrict__ attL, const float* __restrict__ w, const float* __restrict__ bias,
    float* __restrict__ out)
{
  __shared__ __align__(16) short smem[13824];
  short* aS = smem;            // [64 co][72]
  short* bS = smem + 4608;     // [128 l][72]

  int tid = threadIdx.x, lane = tid & 63, wave = tid >> 6;
  int m16 = lane & 15, quad = lane >> 4;
  int l0 = blockIdx.x * 128;
  int cotile = blockIdx.y;
  int b = blockIdx.z;
  int cbase = cotile * 64;

  f32x4 acc[8];
#pragma unroll
  for (int t = 0; t < 8; ++t) acc[t] = (f32x4){0.f, 0.f, 0.f, 0.f};

  for (int ck = 0; ck < 4; ++ck) {
    __syncthreads();
#pragma unroll
    for (int r = 0; r < 4; ++r) {            // A: 64 co x 64 ci from f32, cvt
      int u = r * 256 + tid;
      int c = u >> 4, s4 = u & 15;
      float4 v = *(const float4*)(w + (size_t)(cbase + c) * 256 + ck * 64 + s4 * 4);
      unsigned int p0 = (unsigned int)f2bfbits(v.x) | ((unsigned int)f2bfbits(v.y) << 16);
      unsigned int p1 = (unsigned int)f2bfbits(v.z) | ((unsigned int)f2bfbits(v.w) << 16);
      uint2 u2; u2.x = p0; u2.y = p1;
      *(uint2*)(aS + c * 72 + s4 * 4) = u2;
    }
#pragma unroll
    for (int r = 0; r < 4; ++r) {            // B: 128 l x 64 ci bf16
      int u = r * 256 + tid;
      int l = u >> 3, seg = u & 7;
      *(uint4*)(bS + l * 72 + seg * 8) =
          *(const uint4*)(attL + ((size_t)(b * 1024) + l0 + l) * 256 + ck * 64 + seg * 8);
    }
    __syncthreads();
#pragma unroll
    for (int ks = 0; ks < 2; ++ks) {
      bf16x8 af = *(const bf16x8*)(aS + (wave * 16 + m16) * 72 + ks * 32 + quad * 8);
#pragma unroll
      for (int t = 0; t < 8; ++t) {
        bf16x8 bf = *(const bf16x8*)(bS + (t * 16 + m16) * 72 + ks * 32 + quad * 8);
        acc[t] = __builtin_amdgcn_mfma_f32_16x16x32_bf16(af, bf, acc[t], 0, 0, 0);
      }
    }
  }

  int co = cbase + wave * 16 + quad * 4;
#pragma unroll
  for (int i = 0; i < 4; ++i) {
    float bv = bias[co + i];
    size_t obase = ((size_t)(b * 512) + 256 + co + i) * 1024 + l0;
#pragma unroll
    for (int t = 0; t < 8; ++t)
      out[obase + t * 16 + m16] = acc[t][i] + bv;
  }
}

// ---------------------------------------------------------------------------
extern "C" void kernel_launch(void* const* d_in, const int* in_sizes, int n_in,
                              void* d_out, int out_size, void* d_ws, size_t ws_size,
                              hipStream_t stream) {
  const float* x      = (const float*)d_in[0];
  const float* w_qkv  = (const float*)d_in[1];
  const float* b_qkv  = (const float*)d_in[2];
  const float* w_attn = (const float*)d_in[3];
  const float* b_attn = (const float*)d_in[4];
  const float* w_out  = (const float*)d_in[5];
  const float* b_out  = (const float*)d_in[6];
  const float* krw    = (const float*)d_in[7];
  const float* krh    = (const float*)d_in[8];
  float* out = (float*)d_out;

  bf16* ws    = (bf16*)d_ws;
  bf16* xT    = ws;                 // [0, 2,097,152)  read by fused conv3+qkv
  bf16* attL  = ws;                 // alias of xT     (attn -> attnout, after fused)
  bf16* qT    = ws + 2097152;       // [2,097,152, 4,194,304)
  bf16* kR    = ws + 4194304;       // [4,194,304, 6,291,456)
  bf16* vW    = ws + 6291456;       // [6,291,456, 8,388,608)  exact 16 MB fit

  // wo_bf in d_out's attention half (dead until attnout overwrites it):
  // wob0: batch0 ch256+ region (262,144 floats) holds 28 chunkblks (516,096 bf16).
  // wob1: batch1 ch256+ region holds 4 chunkblks (73,728 bf16).
  bf16* wob0 = (bf16*)(out + (size_t)(0 * 512 + 256) * 1024);
  bf16* wob1 = (bf16*)(out + (size_t)(1 * 512 + 256) * 1024);

  prep_kernel<<<dim3(2084), 256, 0, stream>>>(x, w_out, xT, wob0, wob1);
  convqkv_kernel<<<dim3(1024), 256, 0, stream>>>(xT, wob0, wob1, b_out, out,
                                                 w_qkv, b_qkv, qT, kR, vW);
  attn_mfma_kernel<<<dim3(1024), 256, 0, stream>>>(qT, kR, vW, krw, krh, attL);
  attnout_mfma_kernel<<<dim3(8, 4, 8), 256, 0, stream>>>(attL, w_attn, b_attn, out);
}

// Round 12
// 151.764 us; speedup vs baseline: 1.3625x; 1.0752x over previous
//
#include <hip/hip_runtime.h>
#include <hip/hip_bf16.h>

// AttentionConv2d: B=8, C_IN=256, H=W=32 (HW=1024), DK=DV=256, NH=8, DKH=DVH=32,
// C_OUT=512, 3x3 conv pad=1. fp32 storage in/out; bf16 intermediates + MFMA.
//
// Workspace (bf16 elements, EXACTLY 16 MB):
//   xT    [8 b][1024 l][256 ci]  @ 0          read by fused conv3+qkv
//   attL  [8 b][1024 l][256 ch]  @ 0          alias of xT (attn writes after fused done)
//   qT    [64 head][1024][32]    @ 2,097,152
//   kR    [64 head][1024][32]    @ 4,194,304
//   vW    [64 head][32][1024]    @ 6,291,456
// wo_bf (prepacked bf16 conv3 weights) lives in D_OUT's attention half (ch256+),
// dead from launch until attnout overwrites it (wob0: b0 region 28 chunkblks,
// wob1: b1 region 4 chunkblks). prep -> convqkv(fused) -> attn -> attnout.
// R12: attn rel logits moved out of MFMA (no one-hot aug): RW chunk-invariant in
// regs, RH 2 broadcast b128/chunk; prologue table dots float4-vectorized.

typedef __hip_bfloat16 bf16;
typedef __attribute__((ext_vector_type(8))) short bf16x8;
typedef __attribute__((ext_vector_type(4))) float f32x4;

__device__ __forceinline__ float bf2f(bf16 v) { return __bfloat162float(v); }
__device__ __forceinline__ float blo(unsigned int v) { return __uint_as_float(v << 16); }
__device__ __forceinline__ float bhi(unsigned int v) { return __uint_as_float(v & 0xffff0000u); }
__device__ __forceinline__ unsigned short f2bfbits(float f) {
  union { bf16 h; unsigned short u; } cv; cv.h = __float2bfloat16(f); return cv.u;
}
// cheap round-to-nearest (ties away): 2 VALU ops; <=1 ulp vs RNE.
__device__ __forceinline__ short f2bfr(float f) {
  return (short)((__float_as_uint(f) + 0x8000u) >> 16);
}

// ---------------------------------------------------------------------------
// K0: prep — xT transpose to bf16 + w_out bf16 chunk-blocked into wob0/wob1.
// blocks 0..2047: xT; 2048..2083: w_out. grid 2084.
// ---------------------------------------------------------------------------
__global__ __launch_bounds__(256) void prep_kernel(
    const float* __restrict__ x, const float* __restrict__ wout,
    bf16* __restrict__ xT, bf16* __restrict__ wob0, bf16* __restrict__ wob1)
{
  int bid = blockIdx.x, tid = threadIdx.x;
  if (bid < 2048) {
    __shared__ float t[32 * 33];
    int b = bid >> 8, rem = bid & 255;
    int ci0 = (rem >> 5) * 32, l0 = (rem & 31) * 32;
    {
      int ciL = tid >> 3, lL4 = (tid & 7) * 4;
      float4 v = *(const float4*)(x + (size_t)(b * 256 + ci0 + ciL) * 1024 + l0 + lL4);
      t[ciL * 33 + lL4 + 0] = v.x; t[ciL * 33 + lL4 + 1] = v.y;
      t[ciL * 33 + lL4 + 2] = v.z; t[ciL * 33 + lL4 + 3] = v.w;
    }
    __syncthreads();
    {
      int lL = tid >> 3, cS = (tid & 7) * 4;
      unsigned int p0 = (unsigned int)f2bfbits(t[(cS + 0) * 33 + lL]) |
                        ((unsigned int)f2bfbits(t[(cS + 1) * 33 + lL]) << 16);
      unsigned int p1 = (unsigned int)f2bfbits(t[(cS + 2) * 33 + lL]) |
                        ((unsigned int)f2bfbits(t[(cS + 3) * 33 + lL]) << 16);
      uint2 u2; u2.x = p0; u2.y = p1;
      *(uint2*)(xT + ((size_t)(b * 1024) + l0 + lL) * 256 + ci0 + cS) = u2;
    }
  } else {
    int t0 = (bid - 2048) * 256 + tid;       // 0..9215
#pragma unroll
    for (int s = 0; s < 8; ++s) {
      int u = s * 9216 + t0;                 // dst uint4 index 0..73727
      int chunkblk = u / 2304;
      int within = u - chunkblk * 2304;
      int co63 = within / 36;
      int r = within - co63 * 36;            // kidx*4 + cig
      int kidx = r >> 2, cig = r & 3;
      int co = (chunkblk >> 3) * 64 + co63;
      int ci = (chunkblk & 7) * 32 + cig * 8;
      union { unsigned short h[8]; uint4 u4; } pk;
#pragma unroll
      for (int j = 0; j < 8; ++j)
        pk.h[j] = f2bfbits(wout[(size_t)(co * 256 + ci + j) * 9 + kidx]);
      bf16* dst = (chunkblk < 28) ? (wob0 + (size_t)chunkblk * 18432)
                                  : (wob1 + (size_t)(chunkblk - 28) * 18432);
      *(uint4*)(dst + (size_t)within * 8) = pk.u4;
    }
  }
}

// ---------------------------------------------------------------------------
// K1 (fused): blocks 0..255 = conv3 (3x3, MFMA shift-GEMM, prepacked weights);
// 256..1023 = qkv GEMM. Both only read xT -> co-resident, mutual latency hiding.
// ---------------------------------------------------------------------------
__global__ __launch_bounds__(256) void convqkv_kernel(
    const bf16* __restrict__ xT,
    const bf16* __restrict__ wob0, const bf16* __restrict__ wob1,
    const float* __restrict__ b_out, float* __restrict__ out,
    const float* __restrict__ wq, const float* __restrict__ b_qkv,
    bf16* __restrict__ qT, bf16* __restrict__ kR, bf16* __restrict__ vW)
{
  __shared__ __align__(16) short smem[27104];
  int tid = threadIdx.x, lane = tid & 63, wave = tid >> 6;
  int m16 = lane & 15, quad = lane >> 4;

  if (blockIdx.x < 256) {
    short* wS = smem;            // [64 co][296]
    short* xS = smem + 18944;    // [6 rows][34 cols][40]
    int bid = blockIdx.x;
    int rc = bid & 7, cotile = (bid >> 3) & 3, b = bid >> 5;
    int y0 = rc * 4;

    f32x4 acc[8];
#pragma unroll
    for (int t = 0; t < 8; ++t) acc[t] = (f32x4){0.f, 0.f, 0.f, 0.f};

    for (int ck = 0; ck < 8; ++ck) {
      __syncthreads();
      int cb = cotile * 8 + ck;
      const bf16* wbase = (cb < 28) ? (wob0 + (size_t)cb * 18432)
                                    : (wob1 + (size_t)(cb - 28) * 18432);
#pragma unroll
      for (int r = 0; r < 9; ++r) {
        int u = r * 256 + tid;
        *(uint4*)(wS + (u / 36) * 296 + (u % 36) * 8) = *(const uint4*)(wbase + (size_t)u * 8);
      }
#pragma unroll
      for (int r = 0; r < 3; ++r) {
        int u = r * 256 + tid;
        int pos = u >> 2, seg = u & 3;
        int row = pos >> 5, col = pos & 31;
        int gy = y0 - 1 + row;
        uint4 val = make_uint4(0u, 0u, 0u, 0u);
        if (gy >= 0 && gy < 32)
          val = *(const uint4*)(xT + ((size_t)(b * 1024) + gy * 32 + col) * 256 + ck * 32 + seg * 8);
        *(uint4*)(xS + (row * 34 + col + 1) * 40 + seg * 8) = val;
      }
      if (tid < 48) {
        int pos = tid >> 2, seg = tid & 3;
        int row = pos >> 1, side = pos & 1;
        *(uint4*)(xS + (row * 34 + side * 33) * 40 + seg * 8) = make_uint4(0u, 0u, 0u, 0u);
      }
      __syncthreads();
#pragma unroll
      for (int kidx = 0; kidx < 9; ++kidx) {
        int dy = kidx / 3, dx = kidx - dy * 3;
        bf16x8 af = *(const bf16x8*)(wS + (wave * 16 + m16) * 296 + kidx * 32 + quad * 8);
#pragma unroll
        for (int t = 0; t < 8; ++t) {
          int row = (t >> 1) + dy;
          int col = (t & 1) * 16 + m16 + dx;
          bf16x8 bf = *(const bf16x8*)(xS + (row * 34 + col) * 40 + quad * 8);
          acc[t] = __builtin_amdgcn_mfma_f32_16x16x32_bf16(af, bf, acc[t], 0, 0, 0);
        }
      }
    }

    int cob = cotile * 64 + wave * 16 + quad * 4;
#pragma unroll
    for (int i = 0; i < 4; ++i) {
      float bv = b_out[cob + i];
#pragma unroll
      for (int t = 0; t < 8; ++t) {
        int y = y0 + (t >> 1), xc = (t & 1) * 16 + m16;
        out[((size_t)(b * 512) + cob + i) * 1024 + y * 32 + xc] = acc[t][i] + bv;
      }
    }
  } else {
    short* aS = smem;            // [64][72]
    short* bS = smem + 4608;     // [128][72]
    int bid2 = blockIdx.x - 256;
    int ltile = bid2 & 7;
    int rest = bid2 >> 3;
    int ctile = rest % 12;
    int b = rest / 12;
    int l0 = ltile * 128;
    int cbase = ctile * 64;

    f32x4 acc[8];
#pragma unroll
    for (int t = 0; t < 8; ++t) acc[t] = (f32x4){0.f, 0.f, 0.f, 0.f};

    for (int ck = 0; ck < 4; ++ck) {
      __syncthreads();
#pragma unroll
      for (int r = 0; r < 4; ++r) {
        int u = r * 256 + tid;
        int c = u >> 4, s4 = u & 15;
        float4 v = *(const float4*)(wq + (size_t)(cbase + c) * 256 + ck * 64 + s4 * 4);
        unsigned int p0 = (unsigned int)f2bfbits(v.x) | ((unsigned int)f2bfbits(v.y) << 16);
        unsigned int p1 = (unsigned int)f2bfbits(v.z) | ((unsigned int)f2bfbits(v.w) << 16);
        uint2 u2; u2.x = p0; u2.y = p1;
        *(uint2*)(aS + c * 72 + s4 * 4) = u2;
      }
#pragma unroll
      for (int r = 0; r < 4; ++r) {
        int u = r * 256 + tid;
        int l = u >> 3, seg = u & 7;
        *(uint4*)(bS + l * 72 + seg * 8) =
            *(const uint4*)(xT + ((size_t)(b * 1024) + l0 + l) * 256 + ck * 64 + seg * 8);
      }
      __syncthreads();
#pragma unroll
      for (int ks = 0; ks < 2; ++ks) {
        bf16x8 af = *(const bf16x8*)(aS + (wave * 16 + m16) * 72 + ks * 32 + quad * 8);
#pragma unroll
        for (int t = 0; t < 8; ++t) {
          bf16x8 bf = *(const bf16x8*)(bS + (t * 16 + m16) * 72 + ks * 32 + quad * 8);
          acc[t] = __builtin_amdgcn_mfma_f32_16x16x32_bf16(af, bf, acc[t], 0, 0, 0);
        }
      }
    }

    __syncthreads();
    short* ldsT = smem + wave * 3072;
    int cb = cbase + wave * 16;
    bool isq = (ctile < 4);
    float bv[4];
#pragma unroll
    for (int i = 0; i < 4; ++i) bv[i] = b_qkv[cb + quad * 4 + i];
#pragma unroll
    for (int t = 0; t < 8; ++t) {
#pragma unroll
      for (int i = 0; i < 4; ++i) {
        float v = acc[t][i] + bv[i];
        if (isq) v *= 0.17677669529663689f;  // 32^-0.5, pre-rel-logits
        ldsT[(t * 16 + m16) * 24 + quad * 4 + i] = (short)f2bfbits(v);
      }
    }
    if (ctile < 8) {
      bf16* dst = isq ? qT : kR;
      int coff = isq ? cb : cb - 256;
#pragma unroll
      for (int rep = 0; rep < 4; ++rep) {
        int u = rep * 64 + lane;
        int l = u >> 1, half = u & 1;
        int c0 = coff + half * 8;
        int head = b * 8 + (c0 >> 5), d0 = c0 & 31;
        *(uint4*)(dst + ((size_t)head * 1024 + l0 + l) * 32 + d0) =
            *(const uint4*)(ldsT + l * 24 + half * 8);
      }
    } else {
      int dcol = lane >> 2, lg = lane & 3;
      int c2 = (cb - 512) + dcol;
      int head = b * 8 + (c2 >> 5), gd = c2 & 31;
#pragma unroll
      for (int s = 0; s < 4; ++s) {
        union { unsigned int w[4]; uint4 u4; } pk;
#pragma unroll
        for (int p = 0; p < 4; ++p) {
          int j0 = lg * 32 + s * 8 + p * 2;
          unsigned int u0 = (unsigned short)ldsT[j0 * 24 + dcol];
          unsigned int u1 = (unsigned short)ldsT[(j0 + 1) * 24 + dcol];
          pk.w[p] = u0 | (u1 << 16);
        }
        *(uint4*)(vW + ((size_t)head * 32 + gd) * 1024 + l0 + lg * 32 + s * 8) = pk.u4;
      }
    }
  }
}

// ---------------------------------------------------------------------------
// K3: MFMA attention. R12: rel logits OUT of MFMA — 4 k-only QK MFMAs/chunk;
// RW added from chunk-invariant registers, RH from 2 broadcast b128 LDS reads.
// Prologue tables computed with float4-vectorized dots (f32 precision).
// LDS map (27648 B):
//   kS   [64 key][40] shorts @ 0      (5120)   } prologue aliases these as
//   vtS  [32 d][72] shorts  @ 5120    (4608)   } stgF f32 [63][36] (9072)
//   rhS  f32 [32 j][68 r]   @ 9728    (8704)
//   rwS  f32 [64 r][36 j]   @ 18432   (9216)   K-loop aliases as pS (4x1152 sh)
// ---------------------------------------------------------------------------
__global__ __launch_bounds__(256) void attn_mfma_kernel(
    const bf16* __restrict__ qT, const bf16* __restrict__ kR, const bf16* __restrict__ vW,
    const float* __restrict__ krw, const float* __restrict__ krh,
    bf16* __restrict__ attL)
{
  __shared__ __align__(16) char smem[27648];
  short* kS   = (short*)smem;
  short* vtS  = (short*)(smem + 5120);
  float* stgF = (float*)smem;
  float* rhS  = (float*)(smem + 9728);
  float* rwS  = (float*)(smem + 18432);

  int tid = threadIdx.x;
  int lane = tid & 63, wave = tid >> 6;
  int m16 = lane & 15, quad = lane >> 4;
  int bid = blockIdx.x;
  // same head -> same blockIdx mod 8 -> same XCD (round-robin heuristic)
  int head = ((bid & 7) << 3) | ((bid >> 3) & 7);
  int qt = bid >> 6;
  int row0 = qt * 64;
  int b = head >> 3, h = head & 7;

  // staging roles + chunk-0 global prefetch (latency hidden by prologue)
  int skey = tid >> 2, sseg = tid & 3;       // K: 64 keys x 4 segs of 8
  int svd = tid >> 3, svk = tid & 7;         // V: 32 d x 8 key-segs of 8
  const bf16* kptr = kR + (size_t)head * 32768 + skey * 32 + sseg * 8;
  const bf16* vptr = vW + (size_t)head * 32768 + svd * 1024 + svk * 8;
  uint4 kreg = *(const uint4*)kptr;
  uint4 vreg = *(const uint4*)vptr;

  // per-thread prologue identity: row r, j-segment
  int r = tid >> 2, jseg = tid & 3;
  float q32[32];
  {
    const bf16* qp = qT + ((size_t)head * 1024 + row0 + r) * 32;
#pragma unroll
    for (int s4 = 0; s4 < 4; ++s4) {
      uint4 u = ((const uint4*)qp)[s4];
      q32[s4 * 8 + 0] = blo(u.x); q32[s4 * 8 + 1] = bhi(u.x);
      q32[s4 * 8 + 2] = blo(u.y); q32[s4 * 8 + 3] = bhi(u.y);
      q32[s4 * 8 + 4] = blo(u.z); q32[s4 * 8 + 5] = bhi(u.z);
      q32[s4 * 8 + 6] = blo(u.w); q32[s4 * 8 + 7] = bhi(u.w);
    }
  }

  // ---- P0: stage krw f32 (stride 36) ----
  for (int i = tid; i < 504; i += 256) {
    int row = i >> 3, d0 = (i & 7) * 4;
    *(float4*)(stgF + row * 36 + d0) = *(const float4*)(krw + row * 32 + d0);
  }
  __syncthreads();

  // ---- P1: rwS[r][j] = q[r] . krw[j - (r&31) + 31], float4 dots ----
  {
    int qi = r & 31;
#pragma unroll
    for (int jj2 = 0; jj2 < 2; ++jj2) {
      float rv[4];
#pragma unroll
      for (int jp = 0; jp < 4; ++jp) {
        int j = jseg * 8 + jj2 * 4 + jp;
        const float* kw = stgF + (j - qi + 31) * 36;
        float s1 = 0.f;
#pragma unroll
        for (int d4 = 0; d4 < 8; ++d4) {
          float4 kv = *(const float4*)(kw + d4 * 4);
          s1 += q32[d4 * 4 + 0] * kv.x + q32[d4 * 4 + 1] * kv.y +
                q32[d4 * 4 + 2] * kv.z + q32[d4 * 4 + 3] * kv.w;
        }
        rv[jp] = s1;
      }
      *(float4*)(rwS + r * 36 + jseg * 8 + jj2 * 4) = make_float4(rv[0], rv[1], rv[2], rv[3]);
    }
  }
  __syncthreads();

  // ---- P2: stage krh over stgF ----
  for (int i = tid; i < 504; i += 256) {
    int row = i >> 3, d0 = (i & 7) * 4;
    *(float4*)(stgF + row * 36 + d0) = *(const float4*)(krh + row * 32 + d0);
  }
  __syncthreads();

  // ---- P3: rhS[j][r] = q[r] . krh[j - qx + 31] (col-major for b128 loop reads)
  {
    int qx = qt * 2 + (r >> 5);
#pragma unroll
    for (int jj = 0; jj < 8; ++jj) {
      int j = jseg * 8 + jj;
      const float* kh = stgF + (j - qx + 31) * 36;
      float s2 = 0.f;
#pragma unroll
      for (int d4 = 0; d4 < 8; ++d4) {
        float4 kv = *(const float4*)(kh + d4 * 4);
        s2 += q32[d4 * 4 + 0] * kv.x + q32[d4 * 4 + 1] * kv.y +
              q32[d4 * 4 + 2] * kv.z + q32[d4 * 4 + 3] * kv.w;
      }
      rhS[j * 68 + r] = s2;
    }
  }
  __syncthreads();

  // ---- P4: A-frag (q, direct from global) + chunk-invariant RW registers ----
  bf16x8 afrag = *(const bf16x8*)(
      qT + ((size_t)head * 1024 + row0 + wave * 16 + m16) * 32 + quad * 8);
  float rwreg[2][4];
#pragma unroll
  for (int par = 0; par < 2; ++par)
#pragma unroll
    for (int i = 0; i < 4; ++i)
      rwreg[par][i] = rwS[(wave * 16 + quad * 4 + i) * 36 + par * 16 + m16];
  // rwS-region reads complete before any pS write: compiler emits full waitcnt
  // before the K-loop's first s_barrier.

  f32x4 oacc[2];
  oacc[0] = (f32x4){0.f, 0.f, 0.f, 0.f};
  oacc[1] = (f32x4){0.f, 0.f, 0.f, 0.f};
  float rsp[4] = {0.f, 0.f, 0.f, 0.f};
  short* pS = (short*)(smem + 18432) + wave * 1152;   // [16 q][72 key-padded]

  for (int c = 0; c < 16; ++c) {
    __syncthreads();                          // prev compute done reading LDS
    *(uint4*)(kS + skey * 40 + sseg * 8) = kreg;
    *(uint4*)(vtS + svd * 72 + svk * 8) = vreg;
    if (c < 15) {                             // prefetch next chunk
      kreg = *(const uint4*)(kptr + (c + 1) * 2048);
      vreg = *(const uint4*)(vptr + (c + 1) * 64);
    }
    __syncthreads();                          // staging visible

    // RH for this chunk: broadcast b128 reads (rows consecutive)
    float4 rh0 = *(const float4*)(rhS + (c * 2 + 0) * 68 + wave * 16 + quad * 4);
    float4 rh1 = *(const float4*)(rhS + (c * 2 + 1) * 68 + wave * 16 + quad * 4);
    float rhv[2][4] = {{rh0.x, rh0.y, rh0.z, rh0.w}, {rh1.x, rh1.y, rh1.z, rh1.w}};

    // QK^T: 4 n-tiles, k-part only
    f32x4 sacc[4];
#pragma unroll
    for (int t = 0; t < 4; ++t) {
      bf16x8 bfK = *(const bf16x8*)(kS + (t * 16 + m16) * 40 + quad * 8);
      f32x4 z = (f32x4){0.f, 0.f, 0.f, 0.f};
      sacc[t] = __builtin_amdgcn_mfma_f32_16x16x32_bf16(afrag, bfK, z, 0, 0, 0);
    }
    // exp(s + rw + rh) (no max-sub: logits bounded), rsp partials, P -> LDS
#pragma unroll
    for (int t = 0; t < 4; ++t) {
#pragma unroll
      for (int i = 0; i < 4; ++i) {
        float e = __expf(sacc[t][i] + rwreg[t & 1][i] + rhv[t >> 1][i]);
        rsp[i] += e;
        pS[(quad * 4 + i) * 72 + t * 16 + m16] = f2bfr(e);
      }
    }
    // PV: 2 k-steps (32 keys) x 2 d-tiles; same-wave LDS roundtrip
#pragma unroll
    for (int ks2 = 0; ks2 < 2; ++ks2) {
      bf16x8 pf = *(const bf16x8*)(pS + m16 * 72 + ks2 * 32 + quad * 8);
#pragma unroll
      for (int dt = 0; dt < 2; ++dt) {
        bf16x8 vf = *(const bf16x8*)(vtS + (dt * 16 + m16) * 72 + ks2 * 32 + quad * 8);
        oacc[dt] = __builtin_amdgcn_mfma_f32_16x16x32_bf16(pf, vf, oacc[dt], 0, 0, 0);
      }
    }
  }

  // ---- epilogue: reduce row-sums within quad, normalize, store ----
#pragma unroll
  for (int off = 1; off < 16; off <<= 1)
#pragma unroll
    for (int i = 0; i < 4; ++i) rsp[i] += __shfl_xor(rsp[i], off, 64);
#pragma unroll
  for (int i = 0; i < 4; ++i) {
    float invs = 1.0f / rsp[i];
    int grow = row0 + wave * 16 + quad * 4 + i;
#pragma unroll
    for (int dt = 0; dt < 2; ++dt) {
      attL[((size_t)b * 1024 + grow) * 256 + h * 32 + dt * 16 + m16] =
          __float2bfloat16(oacc[dt][i] * invs);
    }
  }
}

// ---------------------------------------------------------------------------
// K4: attnout 1x1 conv as MFMA GEMM 256 x 1024 x 256 per batch. (R6 version)
// Runs last; overwrites the d_out ch256+ regions that hosted wo_bf.
// ---------------------------------------------------------------------------
__global__ __launch_bounds__(256) void attnout_mfma_kernel(
    const bf16* __restrict__ attL, const float* __restrict__ w, const float* __restrict__ bias,
    float* __restrict__ out)
{
  __shared__ __align__(16) short smem[13824];
  short* aS = smem;            // [64 co][72]
  short* bS = smem + 4608;     // [128 l][72]

  int tid = threadIdx.x, lane = tid & 63, wave = tid >> 6;
  int m16 = lane & 15, quad = lane >> 4;
  int l0 = blockIdx.x * 128;
  int cotile = blockIdx.y;
  int b = blockIdx.z;
  int cbase = cotile * 64;

  f32x4 acc[8];
#pragma unroll
  for (int t = 0; t < 8; ++t) acc[t] = (f32x4){0.f, 0.f, 0.f, 0.f};

  for (int ck = 0; ck < 4; ++ck) {
    __syncthreads();
#pragma unroll
    for (int r = 0; r < 4; ++r) {
      int u = r * 256 + tid;
      int c = u >> 4, s4 = u & 15;
      float4 v = *(const float4*)(w + (size_t)(cbase + c) * 256 + ck * 64 + s4 * 4);
      unsigned int p0 = (unsigned int)f2bfbits(v.x) | ((unsigned int)f2bfbits(v.y) << 16);
      unsigned int p1 = (unsigned int)f2bfbits(v.z) | ((unsigned int)f2bfbits(v.w) << 16);
      uint2 u2; u2.x = p0; u2.y = p1;
      *(uint2*)(aS + c * 72 + s4 * 4) = u2;
    }
#pragma unroll
    for (int r = 0; r < 4; ++r) {
      int u = r * 256 + tid;
      int l = u >> 3, seg = u & 7;
      *(uint4*)(bS + l * 72 + seg * 8) =
          *(const uint4*)(attL + ((size_t)(b * 1024) + l0 + l) * 256 + ck * 64 + seg * 8);
    }
    __syncthreads();
#pragma unroll
    for (int ks = 0; ks < 2; ++ks) {
      bf16x8 af = *(const bf16x8*)(aS + (wave * 16 + m16) * 72 + ks * 32 + quad * 8);
#pragma unroll
      for (int t = 0; t < 8; ++t) {
        bf16x8 bf = *(const bf16x8*)(bS + (t * 16 + m16) * 72 + ks * 32 + quad * 8);
        acc[t] = __builtin_amdgcn_mfma_f32_16x16x32_bf16(af, bf, acc[t], 0, 0, 0);
      }
    }
  }

  int co = cbase + wave * 16 + quad * 4;
#pragma unroll
  for (int i = 0; i < 4; ++i) {
    float bv = bias[co + i];
    size_t obase = ((size_t)(b * 512) + 256 + co + i) * 1024 + l0;
#pragma unroll
    for (int t = 0; t < 8; ++t)
      out[obase + t * 16 + m16] = acc[t][i] + bv;
  }
}

// ---------------------------------------------------------------------------
extern "C" void kernel_launch(void* const* d_in, const int* in_sizes, int n_in,
                              void* d_out, int out_size, void* d_ws, size_t ws_size,
                              hipStream_t stream) {
  const float* x      = (const float*)d_in[0];
  const float* w_qkv  = (const float*)d_in[1];
  const float* b_qkv  = (const float*)d_in[2];
  const float* w_attn = (const float*)d_in[3];
  const float* b_attn = (const float*)d_in[4];
  const float* w_out  = (const float*)d_in[5];
  const float* b_out  = (const float*)d_in[6];
  const float* krw    = (const float*)d_in[7];
  const float* krh    = (const float*)d_in[8];
  float* out = (float*)d_out;

  bf16* ws    = (bf16*)d_ws;
  bf16* xT    = ws;                 // [0, 2,097,152)  read by fused conv3+qkv
  bf16* attL  = ws;                 // alias of xT     (attn -> attnout, after fused)
  bf16* qT    = ws + 2097152;       // [2,097,152, 4,194,304)
  bf16* kR    = ws + 4194304;       // [4,194,304, 6,291,456)
  bf16* vW    = ws + 6291456;       // [6,291,456, 8,388,608)  exact 16 MB fit

  // wo_bf in d_out's attention half (dead until attnout overwrites it)
  bf16* wob0 = (bf16*)(out + (size_t)(0 * 512 + 256) * 1024);
  bf16* wob1 = (bf16*)(out + (size_t)(1 * 512 + 256) * 1024);

  prep_kernel<<<dim3(2084), 256, 0, stream>>>(x, w_out, xT, wob0, wob1);
  convqkv_kernel<<<dim3(1024), 256, 0, stream>>>(xT, wob0, wob1, b_out, out,
                                                 w_qkv, b_qkv, qT, kR, vW);
  attn_mfma_kernel<<<dim3(1024), 256, 0, stream>>>(qT, kR, vW, krw, krh, attL);
  attnout_mfma_kernel<<<dim3(8, 4, 8), 256, 0, stream>>>(attL, w_attn, b_attn, out);
}